// Round 6
// baseline (152.084 us; speedup 1.0000x reference)
//
#include <hip/hip_runtime.h>
#include <cstdint>
#include <cstddef>

// BasicViTNCA3D: 24^3 cells, C=128, 8 heads x dim16, MLP 512, 2 NCA steps.
// 4 dispatches: packAll, k1 (pe+LN1+qkv, step0), kA x2 (attn..update + next-qkv tail).
// R6: 8-cell blocks (1728 blocks, 256 thr) -> ~17KB LDS, ~27 waves/CU resident
// (R5 measured occupancy 32% with 16-cell/512-thr blocks; kernel latency-bound).
// GEMMs bf16 MFMA 16x16x32 with M=8 (lanes 8-15 duplicate rows, stores lr<8).
#define NCELL 13824

typedef short bf16x8 __attribute__((ext_vector_type(8)));  // 8 bf16 (4 VGPRs)
typedef float f32x4  __attribute__((ext_vector_type(4)));  // MFMA acc

__device__ __forceinline__ unsigned short f2bf(float x) {
  union { float f; uint32_t u; } c; c.f = x;
  uint32_t r = c.u + 0x7fffu + ((c.u >> 16) & 1u);  // RNE
  return (unsigned short)(r >> 16);
}
// 4 consecutive bf16 -> 4 floats (one 8B load)
__device__ __forceinline__ void bf4_to_f(const unsigned short* p, float* f) {
  uint2 v = *(const uint2*)p;
  union { uint32_t u; float x; } c;
  c.u = v.x << 16; f[0] = c.x;  c.u = v.x & 0xffff0000u; f[1] = c.x;
  c.u = v.y << 16; f[2] = c.x;  c.u = v.y & 0xffff0000u; f[3] = c.x;
}

// A-fragment (16x32 tile, A-row = lane&15) from fp32 LDS; rows 8-15 duplicate 0-7
__device__ __forceinline__ bf16x8 afrag_f32(const float* p) {
  float4 u0 = *(const float4*)p;
  float4 u1 = *(const float4*)(p + 4);
  bf16x8 a;
  a[0] = (short)f2bf(u0.x); a[1] = (short)f2bf(u0.y);
  a[2] = (short)f2bf(u0.z); a[3] = (short)f2bf(u0.w);
  a[4] = (short)f2bf(u1.x); a[5] = (short)f2bf(u1.y);
  a[6] = (short)f2bf(u1.z); a[7] = (short)f2bf(u1.w);
  return a;
}

// ---------------- Threefry-2x32 (JAX-compatible) ----------------
__device__ __forceinline__ void tf2x32(uint32_t k0, uint32_t k1,
                                       uint32_t x0, uint32_t x1,
                                       uint32_t& o0, uint32_t& o1) {
  uint32_t k2 = k0 ^ k1 ^ 0x1BD11BDAu;
  x0 += k0; x1 += k1;
#define TFR(r) { x0 += x1; x1 = (x1 << (r)) | (x1 >> (32 - (r))); x1 ^= x0; }
  TFR(13) TFR(15) TFR(26) TFR(6)   x0 += k1; x1 += k2 + 1u;
  TFR(17) TFR(29) TFR(16) TFR(24)  x0 += k2; x1 += k0 + 2u;
  TFR(13) TFR(15) TFR(26) TFR(6)   x0 += k0; x1 += k1 + 3u;
  TFR(17) TFR(29) TFR(16) TFR(24)  x0 += k1; x1 += k2 + 4u;
  TFR(13) TFR(15) TFR(26) TFR(6)   x0 += k2; x1 += k0 + 5u;
#undef TFR
  o0 = x0; o1 = x1;
}

__device__ __forceinline__ float pe_val(int n, int c) {
  int dd = n % 24, ww = (n / 24) % 24, hh = n / 576;
  if (c == 126)
    return sinf((float)hh) + sinf(0.01f * (float)ww) + sinf(0.0001f * (float)dd);
  return cosf((float)hh) + cosf(0.01f * (float)ww) + cosf(0.0001f * (float)dd);
}

// ---------------- packAll: 5 weights -> MFMA B-frag bf16 ----------------
__device__ __forceinline__ void packOne(const float* __restrict__ W, int K, int N,
                                        unsigned short* __restrict__ P, int f) {
  int KT = K >> 5;
  int lane = f & 63;
  int ft = f >> 6;
  int kt = ft % KT, nt = ft / KT;
  int col = nt * 16 + (lane & 15);
  int k0 = kt * 32 + (lane >> 4) * 8;
  uint32_t w[4];
  #pragma unroll
  for (int p = 0; p < 4; ++p) {
    uint32_t lo = f2bf(W[(size_t)(k0 + 2 * p) * N + col]);
    uint32_t hi = f2bf(W[(size_t)(k0 + 2 * p + 1) * N + col]);
    w[p] = lo | (hi << 16);
  }
  uint4 v; v.x = w[0]; v.y = w[1]; v.z = w[2]; v.w = w[3];
  ((uint4*)P)[f] = v;
}

__global__ __launch_bounds__(256) void packAll(
    const float* __restrict__ Wqkv, const float* __restrict__ Wout,
    const float* __restrict__ Wff1, const float* __restrict__ Wff2,
    const float* __restrict__ Whead,
    unsigned short* __restrict__ pQkv, unsigned short* __restrict__ pOut,
    unsigned short* __restrict__ pFF1, unsigned short* __restrict__ pFF2,
    unsigned short* __restrict__ pHead) {
  int f = blockIdx.x * 256 + threadIdx.x;
  if (f < 6144)        packOne(Wqkv, 128, 384, pQkv, f);
  else if (f < 8192)   packOne(Wout, 128, 128, pOut, f - 6144);
  else if (f < 16384)  packOne(Wff1, 128, 512, pFF1, f - 8192);
  else if (f < 24576)  packOne(Wff2, 512, 128, pFF2, f - 16384);
  else if (f < 26624)  packOne(Whead, 128, 128, pHead, f - 24576);
}

// ---------------- K1: pe + LN1 + qkv GEMM (step 0 only), 8 cells/block ----------------
__global__ __launch_bounds__(256, 4) void nca_k1(
    const float* __restrict__ x, const float* __restrict__ ln1s,
    const float* __restrict__ ln1b, const unsigned short* __restrict__ pQkv,
    unsigned short* __restrict__ wqkv,
    const int* __restrict__ steps, int s) {
  if (s >= *steps) return;
  __shared__ float ly[8][132];
  __shared__ float lmean[8], lrstd[8];
  const int t = threadIdx.x;
  const int swz = (blockIdx.x & 7) * 216 + (blockIdx.x >> 3);  // XCD-contiguous
  const int base = swz * 8;
  #pragma unroll
  for (int i = 0; i < 4; ++i) {
    int idx = i * 256 + t;
    int r = idx >> 7, c = idx & 127;
    int n = base + r;
    ly[r][c] = (c < 126) ? x[(size_t)n * 128 + c] : pe_val(n, c);
  }
  __syncthreads();
  { int r = t >> 5, j = t & 31;
    float s1 = 0.f, s2 = 0.f;
    #pragma unroll
    for (int cc = 0; cc < 4; ++cc) { float v = ly[r][j * 4 + cc]; s1 += v; s2 += v * v; }
    #pragma unroll
    for (int off = 1; off < 32; off <<= 1) { s1 += __shfl_xor(s1, off); s2 += __shfl_xor(s2, off); }
    if (j == 0) {
      float m = s1 * (1.f / 128.f);
      float var = s2 * (1.f / 128.f) - m * m;
      lmean[r] = m; lrstd[r] = rsqrtf(var + 1e-5f);
    }
  }
  __syncthreads();
  #pragma unroll
  for (int i = 0; i < 4; ++i) {
    int idx = i * 256 + t;
    int r = idx >> 7, c = idx & 127;
    ly[r][c] = (ly[r][c] - lmean[r]) * lrstd[r] * ln1s[c] + ln1b[c];
  }
  __syncthreads();
  const int w = t >> 6, l = t & 63;
  const int lr = (l >> 4) * 4, lc = l & 15;
  bf16x8 a4[4];
  #pragma unroll
  for (int kt = 0; kt < 4; ++kt)
    a4[kt] = afrag_f32(&ly[l & 7][kt * 32 + (l >> 4) * 8]);
  const bf16x8* B = (const bf16x8*)pQkv;
  #pragma unroll
  for (int q = 0; q < 6; ++q) {
    f32x4 acc = (f32x4){0.f, 0.f, 0.f, 0.f};
    int nt = w * 6 + q;
    #pragma unroll
    for (int kt = 0; kt < 4; ++kt)
      acc = __builtin_amdgcn_mfma_f32_16x16x32_bf16(a4[kt], B[(nt * 4 + kt) * 64 + l], acc, 0, 0, 0);
    if (lr < 8) {
      int col = nt * 16 + lc;
      #pragma unroll
      for (int j = 0; j < 4; ++j)
        wqkv[(size_t)(base + lr + j) * 384 + col] = f2bf(acc[j]);
    }
  }
}

// ---- kA: attn + out-proj + LN2 + FF1 + FF2 + LN3 + head + mask-update + next qkv ----
__global__ __launch_bounds__(256, 4) void nca_kA(
    const unsigned short* __restrict__ qkv, unsigned short* __restrict__ qkvN,
    const unsigned short* __restrict__ pQkv,
    const unsigned short* __restrict__ pOut, const float* __restrict__ bout,
    const float* __restrict__ ln1s, const float* __restrict__ ln1b,
    const float* __restrict__ ln2s, const float* __restrict__ ln2b,
    const unsigned short* __restrict__ pFF1, const float* __restrict__ bff1,
    const unsigned short* __restrict__ pFF2, const float* __restrict__ bff2,
    const float* __restrict__ ln3s, const float* __restrict__ ln3b,
    const unsigned short* __restrict__ pHead, const float* __restrict__ bhead,
    const float* __restrict__ xin, float* __restrict__ xout,
    const int* __restrict__ steps, int s) {
  if (s >= *steps) return;
  __shared__ float lbuf[8][132];            // attn-out -> ln2 -> y3 -> ln3 -> ln1'
  __shared__ float ly2[8][132];             // y2 residual, then x_new (for tail)
  __shared__ unsigned short lh[8][520];     // GELU(FF1) bf16
  __shared__ float lmean[8], lrstd[8], lmask[8];
  const int t = threadIdx.x;
  const int swz = (blockIdx.x & 7) * 216 + (blockIdx.x >> 3);  // XCD-contiguous
  const int base = swz * 8;
  const int w = t >> 6, l = t & 63;
  const int lr = (l >> 4) * 4, lc = l & 15;

  if (t < 8) { // JAX threefry per-cell mask (partitionable random_bits)
    uint32_t kk0, kk1, b0, b1;
    tf2x32(0u, 42u, 0u, (uint32_t)s, kk0, kk1);
    tf2x32(kk0, kk1, 0u, (uint32_t)(base + t), b0, b1);
    uint32_t bits = b0 ^ b1;
    lmask[t] = ((bits >> 9) > 0x400000u) ? 1.0f : 0.0f;
  }
  // ---- attention: 8 cells x 8 heads x 4 quarters = 256 threads ----
  {
    const int cell = t >> 5, head = (t >> 2) & 7, qr = t & 3;
    const int n = base + cell;
    const int dd = n % 24, ww = (n / 24) % 24, hh = n / 576;
    float qf[4];
    bf4_to_f(qkv + (size_t)n * 384 + head * 16 + qr * 4, qf);
    // affine neighbor base: ptr for (di,dj,dk) = center + (di*576+dj*24+dk)*384
    const unsigned short* kc = qkv + (size_t)n * 384 + 128 + head * 16 + qr * 4;
    const unsigned short* vc = qkv + (size_t)n * 384 + 256 + head * 16 + qr * 4;
    float logits[27];
    int idx = 0;
    #pragma unroll
    for (int di = -1; di <= 1; ++di)
    #pragma unroll
    for (int dj = -1; dj <= 1; ++dj)
    #pragma unroll
    for (int dk = -1; dk <= 1; ++dk) {
      bool ok = ((unsigned)(hh + di) < 24u) && ((unsigned)(ww + dj) < 24u) &&
                ((unsigned)(dd + dk) < 24u);
      float dot = 0.f;
      if (ok) {
        float kf[4];
        bf4_to_f(kc + (di * 576 + dj * 24 + dk) * 384, kf);
        dot = qf[0] * kf[0] + qf[1] * kf[1] + qf[2] * kf[2] + qf[3] * kf[3];
      }
      dot += __shfl_xor(dot, 1);
      dot += __shfl_xor(dot, 2);            // full 16-ch dot in all 4 lanes
      logits[idx++] = dot * 0.25f;          // OOB -> logit 0 (zero-padded localize)
    }
    // tree max (depth 5)
    float mx[27];
    #pragma unroll
    for (int j = 0; j < 27; ++j) mx[j] = logits[j];
    #pragma unroll
    for (int off = 16; off >= 1; off >>= 1)
      #pragma unroll
      for (int j = 0; j < 16; ++j)
        if (j < off && j + off < 27) mx[j] = fmaxf(mx[j], mx[j + off]);
    float m = mx[0];
    #pragma unroll
    for (int j = 0; j < 27; ++j) logits[j] = __expf(logits[j] - m);
    // tree sum (depth 5)
    float sm[27];
    #pragma unroll
    for (int j = 0; j < 27; ++j) sm[j] = logits[j];
    #pragma unroll
    for (int off = 16; off >= 1; off >>= 1)
      #pragma unroll
      for (int j = 0; j < 16; ++j)
        if (j < off && j + off < 27) sm[j] += sm[j + off];
    float den = sm[0];
    float av[4] = {0.f, 0.f, 0.f, 0.f};
    idx = 0;
    #pragma unroll
    for (int di = -1; di <= 1; ++di)
    #pragma unroll
    for (int dj = -1; dj <= 1; ++dj)
    #pragma unroll
    for (int dk = -1; dk <= 1; ++dk) {
      bool ok = ((unsigned)(hh + di) < 24u) && ((unsigned)(ww + dj) < 24u) &&
                ((unsigned)(dd + dk) < 24u);
      if (ok) {
        float vf[4];
        bf4_to_f(vc + (di * 576 + dj * 24 + dk) * 384, vf);
        float wgt = logits[idx];
        av[0] += wgt * vf[0]; av[1] += wgt * vf[1];
        av[2] += wgt * vf[2]; av[3] += wgt * vf[3];
      }
      ++idx;
    }
    float inv = 1.f / den;
    float4 r4; r4.x = av[0]*inv; r4.y = av[1]*inv; r4.z = av[2]*inv; r4.w = av[3]*inv;
    *(float4*)&lbuf[cell][head * 16 + qr * 4] = r4;
  }
  __syncthreads();
  // ---- out-proj: wave w -> coltiles w*2, w*2+1 ----
  bf16x8 a4[4];
  #pragma unroll
  for (int kt = 0; kt < 4; ++kt)
    a4[kt] = afrag_f32(&lbuf[l & 7][kt * 32 + (l >> 4) * 8]);
  float xres[4];
  {
    f32x4 acc[2];
    acc[0] = (f32x4){0.f,0.f,0.f,0.f}; acc[1] = (f32x4){0.f,0.f,0.f,0.f};
    const bf16x8* B = (const bf16x8*)pOut;
    #pragma unroll
    for (int kt = 0; kt < 4; ++kt) {
      #pragma unroll
      for (int q = 0; q < 2; ++q)
        acc[q] = __builtin_amdgcn_mfma_f32_16x16x32_bf16(a4[kt], B[((w*2+q) * 4 + kt) * 64 + l], acc[q], 0, 0, 0);
    }
    __syncthreads();  // all frag reads of lbuf done
    if (lr < 8) {
      #pragma unroll
      for (int q = 0; q < 2; ++q) {
        int col = (w * 2 + q) * 16 + lc;
        #pragma unroll
        for (int j = 0; j < 4; ++j) {
          int r = lr + j, n = base + r;
          float xv = xin[(size_t)n * 128 + col];
          if (q == 0) xres[j] = xv;   // keep one col-set? no: xres per q needed
          float resy = (col < 126) ? xv : pe_val(n, col);
          ly2[r][col] = acc[q][j] + bout[col] + resy;
        }
      }
    }
  }
  __syncthreads();
  { // LN2 stats: 32 thr/row, 4 ch each
    int r = t >> 5, j = t & 31;
    float s1 = 0.f, s2 = 0.f;
    #pragma unroll
    for (int cc = 0; cc < 4; ++cc) { float v = ly2[r][j * 4 + cc]; s1 += v; s2 += v * v; }
    #pragma unroll
    for (int off = 1; off < 32; off <<= 1) { s1 += __shfl_xor(s1, off); s2 += __shfl_xor(s2, off); }
    if (j == 0) {
      float m = s1 * (1.f / 128.f);
      float var = s2 * (1.f / 128.f) - m * m;
      lmean[r] = m; lrstd[r] = rsqrtf(var + 1e-5f);
    }
  }
  __syncthreads();
  #pragma unroll
  for (int i = 0; i < 4; ++i) {
    int idx = i * 256 + t;
    int r = idx >> 7, c = idx & 127;
    lbuf[r][c] = (ly2[r][c] - lmean[r]) * lrstd[r] * ln2s[c] + ln2b[c];
  }
  __syncthreads();
  // ---- FF1: wave w -> coltiles w*8..w*8+7, two acc[4] passes; GELU -> lh bf16 ----
  #pragma unroll
  for (int kt = 0; kt < 4; ++kt)
    a4[kt] = afrag_f32(&lbuf[l & 7][kt * 32 + (l >> 4) * 8]);
  {
    const bf16x8* B = (const bf16x8*)pFF1;
    #pragma unroll
    for (int half = 0; half < 2; ++half) {
      f32x4 acc[4];
      #pragma unroll
      for (int q = 0; q < 4; ++q) acc[q] = (f32x4){0.f,0.f,0.f,0.f};
      #pragma unroll
      for (int kt = 0; kt < 4; ++kt) {
        #pragma unroll
        for (int q = 0; q < 4; ++q) {
          int nt = w * 8 + half * 4 + q;
          acc[q] = __builtin_amdgcn_mfma_f32_16x16x32_bf16(a4[kt], B[(nt * 4 + kt) * 64 + l], acc[q], 0, 0, 0);
        }
      }
      if (lr < 8) {
        #pragma unroll
        for (int q = 0; q < 4; ++q) {
          int col = (w * 8 + half * 4 + q) * 16 + lc;
          #pragma unroll
          for (int j = 0; j < 4; ++j) {
            float v = acc[q][j] + bff1[col];
            v = 0.5f * v * (1.f + erff(v * 0.70710678118654752f));
            lh[lr + j][col] = f2bf(v);
          }
        }
      }
    }
  }
  __syncthreads();
  // ---- FF2: K=512, wave w -> coltiles w*2, w*2+1; y3 -> lbuf ----
  {
    f32x4 acc[2];
    acc[0] = (f32x4){0.f,0.f,0.f,0.f}; acc[1] = (f32x4){0.f,0.f,0.f,0.f};
    const bf16x8* B = (const bf16x8*)pFF2;
    #pragma unroll
    for (int kt = 0; kt < 16; ++kt) {
      bf16x8 a = *(const bf16x8*)&lh[l & 7][kt * 32 + (l >> 4) * 8];
      #pragma unroll
      for (int q = 0; q < 2; ++q)
        acc[q] = __builtin_amdgcn_mfma_f32_16x16x32_bf16(a, B[((w*2+q) * 16 + kt) * 64 + l], acc[q], 0, 0, 0);
    }
    __syncthreads();  // lbuf (ln2) fully consumed
    if (lr < 8) {
      #pragma unroll
      for (int q = 0; q < 2; ++q) {
        int col = (w * 2 + q) * 16 + lc;
        #pragma unroll
        for (int j = 0; j < 4; ++j) {
          int r = lr + j;
          lbuf[r][col] = acc[q][j] + bff2[col] + ly2[r][col];
        }
      }
    }
  }
  __syncthreads();
  { // LN3 stats
    int r = t >> 5, j = t & 31;
    float s1 = 0.f, s2 = 0.f;
    #pragma unroll
    for (int cc = 0; cc < 4; ++cc) { float v = lbuf[r][j * 4 + cc]; s1 += v; s2 += v * v; }
    #pragma unroll
    for (int off = 1; off < 32; off <<= 1) { s1 += __shfl_xor(s1, off); s2 += __shfl_xor(s2, off); }
    if (j == 0) {
      float m = s1 * (1.f / 128.f);
      float var = s2 * (1.f / 128.f) - m * m;
      lmean[r] = m; lrstd[r] = rsqrtf(var + 1e-5f);
    }
  }
  __syncthreads();
  #pragma unroll
  for (int i = 0; i < 4; ++i) {   // in-place normalize
    int idx = i * 256 + t;
    int r = idx >> 7, c = idx & 127;
    lbuf[r][c] = (lbuf[r][c] - lmean[r]) * lrstd[r] * ln3s[c] + ln3b[c];
  }
  __syncthreads();
  // ---- head: wave w -> coltiles w*2, w*2+1; dx; masked update; x_new -> ly2 ----
  #pragma unroll
  for (int kt = 0; kt < 4; ++kt)
    a4[kt] = afrag_f32(&lbuf[l & 7][kt * 32 + (l >> 4) * 8]);
  {
    f32x4 acc[2];
    acc[0] = (f32x4){0.f,0.f,0.f,0.f}; acc[1] = (f32x4){0.f,0.f,0.f,0.f};
    const bf16x8* B = (const bf16x8*)pHead;
    #pragma unroll
    for (int kt = 0; kt < 4; ++kt) {
      #pragma unroll
      for (int q = 0; q < 2; ++q)
        acc[q] = __builtin_amdgcn_mfma_f32_16x16x32_bf16(a4[kt], B[((w*2+q) * 4 + kt) * 64 + l], acc[q], 0, 0, 0);
    }
    if (lr < 8) {
      #pragma unroll
      for (int q = 0; q < 2; ++q) {
        int col = (w * 2 + q) * 16 + lc;
        #pragma unroll
        for (int j = 0; j < 4; ++j) {
          int r = lr + j;
          size_t n = base + r;
          float dx = acc[q][j] + bhead[col];
          float xn = xin[n * 128 + col] + dx * lmask[r];
          xout[n * 128 + col] = xn;
          ly2[r][col] = xn;
        }
      }
    }
  }
  // ---- tail: next step's pe + LN1 + qkv GEMM (skipped on last step) ----
  if (s + 1 < *steps) {
    __syncthreads();
    if (t < 16) { int r = t >> 1, c = 126 + (t & 1); ly2[r][c] = pe_val(base + r, c); }
    __syncthreads();
    { // LN1 stats
      int r = t >> 5, j = t & 31;
      float s1 = 0.f, s2 = 0.f;
      #pragma unroll
      for (int cc = 0; cc < 4; ++cc) { float v = ly2[r][j * 4 + cc]; s1 += v; s2 += v * v; }
      #pragma unroll
      for (int off = 1; off < 32; off <<= 1) { s1 += __shfl_xor(s1, off); s2 += __shfl_xor(s2, off); }
      if (j == 0) {
        float m = s1 * (1.f / 128.f);
        float var = s2 * (1.f / 128.f) - m * m;
        lmean[r] = m; lrstd[r] = rsqrtf(var + 1e-5f);
      }
    }
    __syncthreads();
    #pragma unroll
    for (int i = 0; i < 4; ++i) {
      int idx = i * 256 + t;
      int r = idx >> 7, c = idx & 127;
      lbuf[r][c] = (ly2[r][c] - lmean[r]) * lrstd[r] * ln1s[c] + ln1b[c];
    }
    __syncthreads();
    #pragma unroll
    for (int kt = 0; kt < 4; ++kt)
      a4[kt] = afrag_f32(&lbuf[l & 7][kt * 32 + (l >> 4) * 8]);
    const bf16x8* B = (const bf16x8*)pQkv;
    #pragma unroll
    for (int q = 0; q < 6; ++q) {
      f32x4 acc = (f32x4){0.f,0.f,0.f,0.f};
      int nt = w * 6 + q;
      #pragma unroll
      for (int kt = 0; kt < 4; ++kt)
        acc = __builtin_amdgcn_mfma_f32_16x16x32_bf16(a4[kt], B[(nt * 4 + kt) * 64 + l], acc, 0, 0, 0);
      if (lr < 8) {
        int col = nt * 16 + lc;
        #pragma unroll
        for (int j = 0; j < 4; ++j)
          qkvN[(size_t)(base + lr + j) * 384 + col] = f2bf(acc[j]);
      }
    }
  }
}

extern "C" void kernel_launch(void* const* d_in, const int* in_sizes, int n_in,
                              void* d_out, int out_size, void* d_ws, size_t ws_size,
                              hipStream_t stream) {
  const float* x0   = (const float*)d_in[0];
  const float* Wqkv = (const float*)d_in[1];
  const float* Wout = (const float*)d_in[2];
  const float* bout = (const float*)d_in[3];
  const float* ln1s = (const float*)d_in[4];
  const float* ln1b = (const float*)d_in[5];
  const float* Wff1 = (const float*)d_in[6];
  const float* bff1 = (const float*)d_in[7];
  const float* Wff2 = (const float*)d_in[8];
  const float* bff2 = (const float*)d_in[9];
  const float* ln2s = (const float*)d_in[10];
  const float* ln2b = (const float*)d_in[11];
  const float* ln3s = (const float*)d_in[12];
  const float* ln3b = (const float*)d_in[13];
  const float* Whead= (const float*)d_in[14];
  const float* bhead= (const float*)d_in[15];
  const int*   steps= (const int*)d_in[16];
  float* out = (float*)d_out;

  unsigned short* qkvA = (unsigned short*)d_ws;          // N*384 bf16
  unsigned short* qkvB = qkvA + (size_t)NCELL * 384;     // N*384 bf16
  unsigned short* pQkv = qkvB + (size_t)NCELL * 384;
  unsigned short* pOut = pQkv + 128 * 384;
  unsigned short* pFF1 = pOut + 128 * 128;
  unsigned short* pFF2 = pFF1 + 128 * 512;
  unsigned short* pHead= pFF2 + 512 * 128;

  packAll<<<dim3(104), dim3(256), 0, stream>>>(Wqkv, Wout, Wff1, Wff2, Whead,
                                               pQkv, pOut, pFF1, pFF2, pHead);
  nca_k1<<<dim3(1728), dim3(256), 0, stream>>>(x0, ln1s, ln1b, pQkv, qkvA, steps, 0);
  // s=0: read qkvA, write next-step qkvB; s=1: read qkvB (tail skipped)
  nca_kA<<<dim3(1728), dim3(256), 0, stream>>>(qkvA, qkvB, pQkv, pOut, bout,
                                               ln1s, ln1b, ln2s, ln2b, pFF1, bff1,
                                               pFF2, bff2, ln3s, ln3b, pHead, bhead,
                                               x0, out, steps, 0);
  nca_kA<<<dim3(1728), dim3(256), 0, stream>>>(qkvB, qkvA, pQkv, pOut, bout,
                                               ln1s, ln1b, ln2s, ln2b, pFF1, bff1,
                                               pFF2, bff2, ln3s, ln3b, pHead, bhead,
                                               out, out, steps, 1);
}

// Round 7
// 125.336 us; speedup vs baseline: 1.2134x; 1.2134x over previous
//
#include <hip/hip_runtime.h>
#include <hip/hip_fp16.h>
#include <cstdint>
#include <cstddef>

// BasicViTNCA3D: 24^3 cells, C=128, 8 heads x dim16, MLP 512, 2 NCA steps.
// R7: R5 geometry (16 cells / 512 thr / 864 blocks, bounds (512,4)) + VALU diet:
//  - qkv stored f16; attention dots/PV via __hfma2 packed f16
//  - LN outputs + attn-out stored bf16 in LDS -> MFMA A-frags are raw ds_read_b128
//  - LN stats via 32-lane butterfly fused with normalize (no lmean/lrstd LDS)
//  - fast tanh-GELU (inf-safe) instead of erff
#define NCELL 13824

typedef short bf16x8 __attribute__((ext_vector_type(8)));  // 8 bf16 (4 VGPRs)
typedef float f32x4  __attribute__((ext_vector_type(4)));  // MFMA acc

__device__ __forceinline__ unsigned short f2bf(float x) {
  union { float f; uint32_t u; } c; c.f = x;
  uint32_t r = c.u + 0x7fffu + ((c.u >> 16) & 1u);  // RNE
  return (unsigned short)(r >> 16);
}

// A-fragment (16x32 tile, row = lane&15, k = (lane>>4)*8+j) from fp32 LDS row
__device__ __forceinline__ bf16x8 afrag_f32(const float* p) {
  float4 u0 = *(const float4*)p;
  float4 u1 = *(const float4*)(p + 4);
  bf16x8 a;
  a[0] = (short)f2bf(u0.x); a[1] = (short)f2bf(u0.y);
  a[2] = (short)f2bf(u0.z); a[3] = (short)f2bf(u0.w);
  a[4] = (short)f2bf(u1.x); a[5] = (short)f2bf(u1.y);
  a[6] = (short)f2bf(u1.z); a[7] = (short)f2bf(u1.w);
  return a;
}

// load 2x __half2 (8B) from f16 pointer
__device__ __forceinline__ void ldh2x2(const __half* p, __half2& a, __half2& b) {
  uint2 u = *(const uint2*)p;
  union { uint32_t u; __half2 h; } c0, c1;
  c0.u = u.x; c1.u = u.y;
  a = c0.h; b = c1.h;
}

// inf-safe tanh-form GELU (max abs dev ~1e-3 vs exact erf GELU)
__device__ __forceinline__ float gelu_f(float x) {
  float u = 0.7978845608f * x * (1.f + 0.044715f * x * x);
  float e = __expf(2.f * u);
  float t = 1.f - 2.f / (e + 1.f);   // tanh(u); limits handled via inf arithmetic
  return 0.5f * x * (1.f + t);
}

// ---------------- Threefry-2x32 (JAX-compatible) ----------------
__device__ __forceinline__ void tf2x32(uint32_t k0, uint32_t k1,
                                       uint32_t x0, uint32_t x1,
                                       uint32_t& o0, uint32_t& o1) {
  uint32_t k2 = k0 ^ k1 ^ 0x1BD11BDAu;
  x0 += k0; x1 += k1;
#define TFR(r) { x0 += x1; x1 = (x1 << (r)) | (x1 >> (32 - (r))); x1 ^= x0; }
  TFR(13) TFR(15) TFR(26) TFR(6)   x0 += k1; x1 += k2 + 1u;
  TFR(17) TFR(29) TFR(16) TFR(24)  x0 += k2; x1 += k0 + 2u;
  TFR(13) TFR(15) TFR(26) TFR(6)   x0 += k0; x1 += k1 + 3u;
  TFR(17) TFR(29) TFR(16) TFR(24)  x0 += k1; x1 += k2 + 4u;
  TFR(13) TFR(15) TFR(26) TFR(6)   x0 += k2; x1 += k0 + 5u;
#undef TFR
  o0 = x0; o1 = x1;
}

__device__ __forceinline__ float pe_val(int n, int c) {
  int dd = n % 24, ww = (n / 24) % 24, hh = n / 576;
  if (c == 126)
    return sinf((float)hh) + sinf(0.01f * (float)ww) + sinf(0.0001f * (float)dd);
  return cosf((float)hh) + cosf(0.01f * (float)ww) + cosf(0.0001f * (float)dd);
}

// ---------------- packAll: 5 weights -> MFMA B-frag bf16 ----------------
__device__ __forceinline__ void packOne(const float* __restrict__ W, int K, int N,
                                        unsigned short* __restrict__ P, int f) {
  int KT = K >> 5;
  int lane = f & 63;
  int ft = f >> 6;
  int kt = ft % KT, nt = ft / KT;
  int col = nt * 16 + (lane & 15);
  int k0 = kt * 32 + (lane >> 4) * 8;
  uint32_t w[4];
  #pragma unroll
  for (int p = 0; p < 4; ++p) {
    uint32_t lo = f2bf(W[(size_t)(k0 + 2 * p) * N + col]);
    uint32_t hi = f2bf(W[(size_t)(k0 + 2 * p + 1) * N + col]);
    w[p] = lo | (hi << 16);
  }
  uint4 v; v.x = w[0]; v.y = w[1]; v.z = w[2]; v.w = w[3];
  ((uint4*)P)[f] = v;
}

__global__ __launch_bounds__(256) void packAll(
    const float* __restrict__ Wqkv, const float* __restrict__ Wout,
    const float* __restrict__ Wff1, const float* __restrict__ Wff2,
    const float* __restrict__ Whead,
    unsigned short* __restrict__ pQkv, unsigned short* __restrict__ pOut,
    unsigned short* __restrict__ pFF1, unsigned short* __restrict__ pFF2,
    unsigned short* __restrict__ pHead) {
  int f = blockIdx.x * 256 + threadIdx.x;
  if (f < 6144)        packOne(Wqkv, 128, 384, pQkv, f);
  else if (f < 8192)   packOne(Wout, 128, 128, pOut, f - 6144);
  else if (f < 16384)  packOne(Wff1, 128, 512, pFF1, f - 8192);
  else if (f < 24576)  packOne(Wff2, 512, 128, pFF2, f - 16384);
  else if (f < 26624)  packOne(Whead, 128, 128, pHead, f - 24576);
}

// ---------------- K1: pe + LN1 + qkv GEMM (step 0 only) ----------------
__global__ __launch_bounds__(256) void nca_k1(
    const float* __restrict__ x, const float* __restrict__ ln1s,
    const float* __restrict__ ln1b, const unsigned short* __restrict__ pQkv,
    __half* __restrict__ wqkv,
    const int* __restrict__ steps, int s) {
  if (s >= *steps) return;
  __shared__ float ly[16][132];
  __shared__ float lmean[16], lrstd[16];
  const int t = threadIdx.x;
  const int swz = (blockIdx.x & 7) * 108 + (blockIdx.x >> 3);  // XCD-contiguous
  const int base = swz * 16;
  #pragma unroll
  for (int i = 0; i < 8; ++i) {
    int idx = i * 256 + t;
    int r = idx >> 7, c = idx & 127;
    int n = base + r;
    ly[r][c] = (c < 126) ? x[(size_t)n * 128 + c] : pe_val(n, c);
  }
  __syncthreads();
  { int r = t >> 4, j = t & 15;
    float s1 = 0.f, s2 = 0.f;
    #pragma unroll
    for (int cc = 0; cc < 8; ++cc) { float v = ly[r][j * 8 + cc]; s1 += v; s2 += v * v; }
    #pragma unroll
    for (int off = 1; off < 16; off <<= 1) { s1 += __shfl_xor(s1, off); s2 += __shfl_xor(s2, off); }
    if (j == 0) {
      float m = s1 * (1.f / 128.f);
      float var = s2 * (1.f / 128.f) - m * m;
      lmean[r] = m; lrstd[r] = rsqrtf(var + 1e-5f);
    }
  }
  __syncthreads();
  #pragma unroll
  for (int i = 0; i < 8; ++i) {
    int idx = i * 256 + t;
    int r = idx >> 7, c = idx & 127;
    ly[r][c] = (ly[r][c] - lmean[r]) * lrstd[r] * ln1s[c] + ln1b[c];
  }
  __syncthreads();
  const int w = t >> 6, l = t & 63;
  bf16x8 a4[4];
  #pragma unroll
  for (int kt = 0; kt < 4; ++kt)
    a4[kt] = afrag_f32(&ly[l & 15][kt * 32 + (l >> 4) * 8]);
  const bf16x8* B = (const bf16x8*)pQkv;
  #pragma unroll
  for (int q = 0; q < 6; ++q) {
    f32x4 acc = (f32x4){0.f, 0.f, 0.f, 0.f};
    int nt = w * 6 + q;
    #pragma unroll
    for (int kt = 0; kt < 4; ++kt)
      acc = __builtin_amdgcn_mfma_f32_16x16x32_bf16(a4[kt], B[(nt * 4 + kt) * 64 + l], acc, 0, 0, 0);
    int col = nt * 16 + (l & 15);
    #pragma unroll
    for (int j = 0; j < 4; ++j)
      wqkv[(size_t)(base + (l >> 4) * 4 + j) * 384 + col] = __float2half(acc[j]);
  }
}

// ---- kA: attn + out-proj + LN2 + FF1 + FF2 + LN3 + head + mask-update + next qkv ----
__global__ __launch_bounds__(512, 4) void nca_kA(
    const __half* __restrict__ qkv, __half* __restrict__ qkvN,
    const unsigned short* __restrict__ pQkv,
    const unsigned short* __restrict__ pOut, const float* __restrict__ bout,
    const float* __restrict__ ln1s, const float* __restrict__ ln1b,
    const float* __restrict__ ln2s, const float* __restrict__ ln2b,
    const unsigned short* __restrict__ pFF1, const float* __restrict__ bff1,
    const unsigned short* __restrict__ pFF2, const float* __restrict__ bff2,
    const float* __restrict__ ln3s, const float* __restrict__ ln3b,
    const unsigned short* __restrict__ pHead, const float* __restrict__ bhead,
    const float* __restrict__ xin, float* __restrict__ xout,
    const int* __restrict__ steps, int s) {
  if (s >= *steps) return;
  __shared__ unsigned short lnorm[16][136];  // bf16: attn-out / ln2 / ln3 / ln1'
  __shared__ float ly2[16][132];             // f32: y2 -> y3 (in place) -> x_new
  __shared__ unsigned short lh[16][520];     // bf16: GELU(FF1)
  __shared__ float lmask[16];
  const int t = threadIdx.x;
  const int swz = (blockIdx.x & 7) * 108 + (blockIdx.x >> 3);  // XCD-contiguous
  const int base = swz * 16;
  const int w = t >> 6, l = t & 63;
  const int lr = (l >> 4) * 4, lc = l & 15;

  if (t < 16) { // JAX threefry per-cell mask (partitionable random_bits)
    uint32_t kk0, kk1, b0, b1;
    tf2x32(0u, 42u, 0u, (uint32_t)s, kk0, kk1);
    tf2x32(kk0, kk1, 0u, (uint32_t)(base + t), b0, b1);
    uint32_t bits = b0 ^ b1;
    lmask[t] = ((bits >> 9) > 0x400000u) ? 1.0f : 0.0f;
  }
  // ---- attention: 16 cells x 8 heads x 4 quarters = 512 threads, f16 math ----
  {
    const int cell = t >> 5, head = (t >> 2) & 7, qr = t & 3;
    const int n = base + cell;
    const int dd = n % 24, ww = (n / 24) % 24, hh = n / 576;
    __half2 q0, q1;
    ldh2x2(qkv + (size_t)n * 384 + head * 16 + qr * 4, q0, q1);
    const __half* kc = qkv + (size_t)n * 384 + 128 + head * 16 + qr * 4;
    const __half* vc = qkv + (size_t)n * 384 + 256 + head * 16 + qr * 4;
    const __half2 hz = __float2half2_rn(0.f);
    float logits[27];
    int idx = 0;
    #pragma unroll
    for (int di = -1; di <= 1; ++di)
    #pragma unroll
    for (int dj = -1; dj <= 1; ++dj)
    #pragma unroll
    for (int dk = -1; dk <= 1; ++dk) {
      bool ok = ((unsigned)(hh + di) < 24u) && ((unsigned)(ww + dj) < 24u) &&
                ((unsigned)(dd + dk) < 24u);
      float dot = 0.f;
      if (ok) {
        __half2 k0, k1;
        ldh2x2(kc + (di * 576 + dj * 24 + dk) * 384, k0, k1);
        __half2 d2 = __hfma2(q0, k0, __hfma2(q1, k1, hz));
        dot = __low2float(d2) + __high2float(d2);
      }
      dot += __shfl_xor(dot, 1);
      dot += __shfl_xor(dot, 2);            // full 16-ch dot in all 4 lanes
      logits[idx++] = dot * 0.25f;          // OOB -> logit 0 (zero-padded localize)
    }
    // tree max
    float mx[27];
    #pragma unroll
    for (int j = 0; j < 27; ++j) mx[j] = logits[j];
    #pragma unroll
    for (int off = 16; off >= 1; off >>= 1)
      #pragma unroll
      for (int j = 0; j < 16; ++j)
        if (j < off && j + off < 27) mx[j] = fmaxf(mx[j], mx[j + off]);
    float m = mx[0];
    #pragma unroll
    for (int j = 0; j < 27; ++j) logits[j] = __expf(logits[j] - m);
    float sm[27];
    #pragma unroll
    for (int j = 0; j < 27; ++j) sm[j] = logits[j];
    #pragma unroll
    for (int off = 16; off >= 1; off >>= 1)
      #pragma unroll
      for (int j = 0; j < 16; ++j)
        if (j < off && j + off < 27) sm[j] += sm[j + off];
    float den = sm[0];
    __half2 av0 = __float2half2_rn(0.f), av1 = __float2half2_rn(0.f);
    idx = 0;
    #pragma unroll
    for (int di = -1; di <= 1; ++di)
    #pragma unroll
    for (int dj = -1; dj <= 1; ++dj)
    #pragma unroll
    for (int dk = -1; dk <= 1; ++dk) {
      bool ok = ((unsigned)(hh + di) < 24u) && ((unsigned)(ww + dj) < 24u) &&
                ((unsigned)(dd + dk) < 24u);
      if (ok) {
        __half2 v0, v1;
        ldh2x2(vc + (di * 576 + dj * 24 + dk) * 384, v0, v1);
        __half2 w2 = __float2half2_rn(logits[idx]);
        av0 = __hfma2(w2, v0, av0);
        av1 = __hfma2(w2, v1, av1);
      }
      ++idx;
    }
    float inv = 1.f / den;
    float2 f0 = __half22float2(av0), f1 = __half22float2(av1);
    uint32_t w0 = (uint32_t)f2bf(f0.x * inv) | ((uint32_t)f2bf(f0.y * inv) << 16);
    uint32_t w1 = (uint32_t)f2bf(f1.x * inv) | ((uint32_t)f2bf(f1.y * inv) << 16);
    *(uint2*)&lnorm[cell][head * 16 + qr * 4] = (uint2){w0, w1};
  }
  __syncthreads();
  // ---- out-proj: wave w -> coltile w; epilogue y2 -> ly2 (f32) ----
  bf16x8 a4[4];
  #pragma unroll
  for (int kt = 0; kt < 4; ++kt)
    a4[kt] = *(const bf16x8*)&lnorm[l & 15][kt * 32 + (l >> 4) * 8];
  float xres[4];
  {
    f32x4 acc = (f32x4){0.f,0.f,0.f,0.f};
    const bf16x8* B = (const bf16x8*)pOut;
    #pragma unroll
    for (int kt = 0; kt < 4; ++kt)
      acc = __builtin_amdgcn_mfma_f32_16x16x32_bf16(a4[kt], B[(w * 4 + kt) * 64 + l], acc, 0, 0, 0);
    int col = w * 16 + lc;
    #pragma unroll
    for (int j = 0; j < 4; ++j) {
      int r = lr + j, n = base + r;
      xres[j] = xin[(size_t)n * 128 + col];                 // true x (for final update)
      float resy = (col < 126) ? xres[j] : pe_val(n, col);  // y residual has pe
      ly2[r][col] = acc[j] + bout[col] + resy;
    }
  }
  __syncthreads();
  { // ---- LN2: butterfly stats + normalize own 4 ch -> lnorm bf16 ----
    int r = t >> 5, j = t & 31;
    float v0 = ly2[r][j*4], v1 = ly2[r][j*4+1], v2 = ly2[r][j*4+2], v3 = ly2[r][j*4+3];
    float s1 = v0 + v1 + v2 + v3;
    float s2 = v0*v0 + v1*v1 + v2*v2 + v3*v3;
    #pragma unroll
    for (int off = 1; off < 32; off <<= 1) { s1 += __shfl_xor(s1, off); s2 += __shfl_xor(s2, off); }
    float m = s1 * (1.f / 128.f);
    float rstd = rsqrtf(s2 * (1.f / 128.f) - m * m + 1e-5f);
    float n0 = (v0 - m) * rstd * ln2s[j*4]   + ln2b[j*4];
    float n1 = (v1 - m) * rstd * ln2s[j*4+1] + ln2b[j*4+1];
    float n2 = (v2 - m) * rstd * ln2s[j*4+2] + ln2b[j*4+2];
    float n3 = (v3 - m) * rstd * ln2s[j*4+3] + ln2b[j*4+3];
    uint32_t w0 = (uint32_t)f2bf(n0) | ((uint32_t)f2bf(n1) << 16);
    uint32_t w1 = (uint32_t)f2bf(n2) | ((uint32_t)f2bf(n3) << 16);
    *(uint2*)&lnorm[r][j * 4] = (uint2){w0, w1};
  }
  __syncthreads();
  // ---- FF1: wave w -> coltiles w*4..w*4+3; fast GELU -> lh bf16 ----
  #pragma unroll
  for (int kt = 0; kt < 4; ++kt)
    a4[kt] = *(const bf16x8*)&lnorm[l & 15][kt * 32 + (l >> 4) * 8];
  {
    f32x4 acc[4];
    #pragma unroll
    for (int q = 0; q < 4; ++q) acc[q] = (f32x4){0.f,0.f,0.f,0.f};
    const bf16x8* B = (const bf16x8*)pFF1;
    #pragma unroll
    for (int kt = 0; kt < 4; ++kt) {
      #pragma unroll
      for (int q = 0; q < 4; ++q) {
        int nt = w * 4 + q;
        acc[q] = __builtin_amdgcn_mfma_f32_16x16x32_bf16(a4[kt], B[(nt * 4 + kt) * 64 + l], acc[q], 0, 0, 0);
      }
    }
    #pragma unroll
    for (int q = 0; q < 4; ++q) {
      int col = (w * 4 + q) * 16 + lc;
      #pragma unroll
      for (int j = 0; j < 4; ++j)
        lh[lr + j][col] = f2bf(gelu_f(acc[q][j] + bff1[col]));
    }
  }
  __syncthreads();
  // ---- FF2: K=512, wave w -> coltile w; y3 = acc + b + y2 in place (owner) ----
  {
    f32x4 acc = (f32x4){0.f,0.f,0.f,0.f};
    const bf16x8* B = (const bf16x8*)pFF2;
    #pragma unroll
    for (int kt = 0; kt < 16; ++kt) {
      bf16x8 a = *(const bf16x8*)&lh[l & 15][kt * 32 + (l >> 4) * 8];
      acc = __builtin_amdgcn_mfma_f32_16x16x32_bf16(a, B[(w * 16 + kt) * 64 + l], acc, 0, 0, 0);
    }
    int col = w * 16 + lc;
    #pragma unroll
    for (int j = 0; j < 4; ++j) {
      int r = lr + j;
      ly2[r][col] = acc[j] + bff2[col] + ly2[r][col];
    }
  }
  __syncthreads();
  { // ---- LN3: butterfly stats + normalize -> lnorm bf16 ----
    int r = t >> 5, j = t & 31;
    float v0 = ly2[r][j*4], v1 = ly2[r][j*4+1], v2 = ly2[r][j*4+2], v3 = ly2[r][j*4+3];
    float s1 = v0 + v1 + v2 + v3;
    float s2 = v0*v0 + v1*v1 + v2*v2 + v3*v3;
    #pragma unroll
    for (int off = 1; off < 32; off <<= 1) { s1 += __shfl_xor(s1, off); s2 += __shfl_xor(s2, off); }
    float m = s1 * (1.f / 128.f);
    float rstd = rsqrtf(s2 * (1.f / 128.f) - m * m + 1e-5f);
    float n0 = (v0 - m) * rstd * ln3s[j*4]   + ln3b[j*4];
    float n1 = (v1 - m) * rstd * ln3s[j*4+1] + ln3b[j*4+1];
    float n2 = (v2 - m) * rstd * ln3s[j*4+2] + ln3b[j*4+2];
    float n3 = (v3 - m) * rstd * ln3s[j*4+3] + ln3b[j*4+3];
    uint32_t w0 = (uint32_t)f2bf(n0) | ((uint32_t)f2bf(n1) << 16);
    uint32_t w1 = (uint32_t)f2bf(n2) | ((uint32_t)f2bf(n3) << 16);
    *(uint2*)&lnorm[r][j * 4] = (uint2){w0, w1};
  }
  __syncthreads();
  // ---- head: wave w -> coltile w; dx; masked update; x_new -> ly2 ----
  #pragma unroll
  for (int kt = 0; kt < 4; ++kt)
    a4[kt] = *(const bf16x8*)&lnorm[l & 15][kt * 32 + (l >> 4) * 8];
  {
    f32x4 acc = (f32x4){0.f,0.f,0.f,0.f};
    const bf16x8* B = (const bf16x8*)pHead;
    #pragma unroll
    for (int kt = 0; kt < 4; ++kt)
      acc = __builtin_amdgcn_mfma_f32_16x16x32_bf16(a4[kt], B[(w * 4 + kt) * 64 + l], acc, 0, 0, 0);
    int col = w * 16 + lc;
    #pragma unroll
    for (int j = 0; j < 4; ++j) {
      int r = lr + j;
      size_t n = base + r;
      float dx = acc[j] + bhead[col];
      float xn = xres[j] + dx * lmask[r];
      xout[n * 128 + col] = xn;
      ly2[r][col] = xn;
    }
  }
  // ---- tail: next step's pe + LN1 + qkv GEMM (skipped on last step) ----
  if (s + 1 < *steps) {
    __syncthreads();
    if (t < 32) { int r = t >> 1, c = 126 + (t & 1); ly2[r][c] = pe_val(base + r, c); }
    __syncthreads();
    { // LN1: butterfly stats + normalize -> lnorm bf16
      int r = t >> 5, j = t & 31;
      float v0 = ly2[r][j*4], v1 = ly2[r][j*4+1], v2 = ly2[r][j*4+2], v3 = ly2[r][j*4+3];
      float s1 = v0 + v1 + v2 + v3;
      float s2 = v0*v0 + v1*v1 + v2*v2 + v3*v3;
      #pragma unroll
      for (int off = 1; off < 32; off <<= 1) { s1 += __shfl_xor(s1, off); s2 += __shfl_xor(s2, off); }
      float m = s1 * (1.f / 128.f);
      float rstd = rsqrtf(s2 * (1.f / 128.f) - m * m + 1e-5f);
      float n0 = (v0 - m) * rstd * ln1s[j*4]   + ln1b[j*4];
      float n1 = (v1 - m) * rstd * ln1s[j*4+1] + ln1b[j*4+1];
      float n2 = (v2 - m) * rstd * ln1s[j*4+2] + ln1b[j*4+2];
      float n3 = (v3 - m) * rstd * ln1s[j*4+3] + ln1b[j*4+3];
      uint32_t w0 = (uint32_t)f2bf(n0) | ((uint32_t)f2bf(n1) << 16);
      uint32_t w1 = (uint32_t)f2bf(n2) | ((uint32_t)f2bf(n3) << 16);
      *(uint2*)&lnorm[r][j * 4] = (uint2){w0, w1};
    }
    __syncthreads();
    #pragma unroll
    for (int kt = 0; kt < 4; ++kt)
      a4[kt] = *(const bf16x8*)&lnorm[l & 15][kt * 32 + (l >> 4) * 8];
    const bf16x8* B = (const bf16x8*)pQkv;
    #pragma unroll
    for (int q = 0; q < 3; ++q) {
      f32x4 acc = (f32x4){0.f,0.f,0.f,0.f};
      int nt = w * 3 + q;
      #pragma unroll
      for (int kt = 0; kt < 4; ++kt)
        acc = __builtin_amdgcn_mfma_f32_16x16x32_bf16(a4[kt], B[(nt * 4 + kt) * 64 + l], acc, 0, 0, 0);
      int col = nt * 16 + lc;
      #pragma unroll
      for (int j = 0; j < 4; ++j)
        qkvN[(size_t)(base + lr + j) * 384 + col] = __float2half(acc[j]);
    }
  }
}

extern "C" void kernel_launch(void* const* d_in, const int* in_sizes, int n_in,
                              void* d_out, int out_size, void* d_ws, size_t ws_size,
                              hipStream_t stream) {
  const float* x0   = (const float*)d_in[0];
  const float* Wqkv = (const float*)d_in[1];
  const float* Wout = (const float*)d_in[2];
  const float* bout = (const float*)d_in[3];
  const float* ln1s = (const float*)d_in[4];
  const float* ln1b = (const float*)d_in[5];
  const float* Wff1 = (const float*)d_in[6];
  const float* bff1 = (const float*)d_in[7];
  const float* Wff2 = (const float*)d_in[8];
  const float* bff2 = (const float*)d_in[9];
  const float* ln2s = (const float*)d_in[10];
  const float* ln2b = (const float*)d_in[11];
  const float* ln3s = (const float*)d_in[12];
  const float* ln3b = (const float*)d_in[13];
  const float* Whead= (const float*)d_in[14];
  const float* bhead= (const float*)d_in[15];
  const int*   steps= (const int*)d_in[16];
  float* out = (float*)d_out;

  __half* qkvA = (__half*)d_ws;                          // N*384 f16
  __half* qkvB = qkvA + (size_t)NCELL * 384;             // N*384 f16
  unsigned short* pQkv = (unsigned short*)(qkvB + (size_t)NCELL * 384);
  unsigned short* pOut = pQkv + 128 * 384;
  unsigned short* pFF1 = pOut + 128 * 128;
  unsigned short* pFF2 = pFF1 + 128 * 512;
  unsigned short* pHead= pFF2 + 512 * 128;

  packAll<<<dim3(104), dim3(256), 0, stream>>>(Wqkv, Wout, Wff1, Wff2, Whead,
                                               pQkv, pOut, pFF1, pFF2, pHead);
  nca_k1<<<dim3(864), dim3(256), 0, stream>>>(x0, ln1s, ln1b, pQkv, qkvA, steps, 0);
  // s=0: read qkvA, write next-step qkvB; s=1: read qkvB (tail skipped)
  nca_kA<<<dim3(864), dim3(512), 0, stream>>>(qkvA, qkvB, pQkv, pOut, bout,
                                              ln1s, ln1b, ln2s, ln2b, pFF1, bff1,
                                              pFF2, bff2, ln3s, ln3b, pHead, bhead,
                                              x0, out, steps, 0);
  nca_kA<<<dim3(864), dim3(512), 0, stream>>>(qkvB, qkvA, pQkv, pOut, bout,
                                              ln1s, ln1b, ln2s, ln2b, pFF1, bff1,
                                              pFF2, bff2, ln3s, ln3b, pHead, bhead,
                                              out, out, steps, 1);
}

// Round 8
// 115.382 us; speedup vs baseline: 1.3181x; 1.0863x over previous
//
#include <hip/hip_runtime.h>
#include <hip/hip_fp16.h>
#include <cstdint>
#include <cstddef>

// BasicViTNCA3D: 24^3 cells, C=128, 8 heads x dim16, MLP 512, 2 NCA steps.
// R8 = R7 + attention restructure:
//  - no max-subtraction (logits ~ +-2 by scale analysis; softmax ratios identical)
//  - QK dot + exp + PV fused in ONE 27-neighbor loop, unnormalized accum
//    (den += e, av += e*v; divide at end) -> no logits[27]/tree arrays,
//    all iterations independent -> deep load pipelining, ~60 VGPRs freed.
#define NCELL 13824

typedef short bf16x8 __attribute__((ext_vector_type(8)));  // 8 bf16 (4 VGPRs)
typedef float f32x4  __attribute__((ext_vector_type(4)));  // MFMA acc

__device__ __forceinline__ unsigned short f2bf(float x) {
  union { float f; uint32_t u; } c; c.f = x;
  uint32_t r = c.u + 0x7fffu + ((c.u >> 16) & 1u);  // RNE
  return (unsigned short)(r >> 16);
}

// A-fragment (16x32 tile, row = lane&15, k = (lane>>4)*8+j) from fp32 LDS row
__device__ __forceinline__ bf16x8 afrag_f32(const float* p) {
  float4 u0 = *(const float4*)p;
  float4 u1 = *(const float4*)(p + 4);
  bf16x8 a;
  a[0] = (short)f2bf(u0.x); a[1] = (short)f2bf(u0.y);
  a[2] = (short)f2bf(u0.z); a[3] = (short)f2bf(u0.w);
  a[4] = (short)f2bf(u1.x); a[5] = (short)f2bf(u1.y);
  a[6] = (short)f2bf(u1.z); a[7] = (short)f2bf(u1.w);
  return a;
}

// load 2x __half2 (8B) from f16 pointer
__device__ __forceinline__ void ldh2x2(const __half* p, __half2& a, __half2& b) {
  uint2 u = *(const uint2*)p;
  union { uint32_t u; __half2 h; } c0, c1;
  c0.u = u.x; c1.u = u.y;
  a = c0.h; b = c1.h;
}

// inf-safe tanh-form GELU (max abs dev ~1e-3 vs exact erf GELU)
__device__ __forceinline__ float gelu_f(float x) {
  float u = 0.7978845608f * x * (1.f + 0.044715f * x * x);
  float e = __expf(2.f * u);
  float t = 1.f - 2.f / (e + 1.f);   // tanh(u)
  return 0.5f * x * (1.f + t);
}

// ---------------- Threefry-2x32 (JAX-compatible) ----------------
__device__ __forceinline__ void tf2x32(uint32_t k0, uint32_t k1,
                                       uint32_t x0, uint32_t x1,
                                       uint32_t& o0, uint32_t& o1) {
  uint32_t k2 = k0 ^ k1 ^ 0x1BD11BDAu;
  x0 += k0; x1 += k1;
#define TFR(r) { x0 += x1; x1 = (x1 << (r)) | (x1 >> (32 - (r))); x1 ^= x0; }
  TFR(13) TFR(15) TFR(26) TFR(6)   x0 += k1; x1 += k2 + 1u;
  TFR(17) TFR(29) TFR(16) TFR(24)  x0 += k2; x1 += k0 + 2u;
  TFR(13) TFR(15) TFR(26) TFR(6)   x0 += k0; x1 += k1 + 3u;
  TFR(17) TFR(29) TFR(16) TFR(24)  x0 += k1; x1 += k2 + 4u;
  TFR(13) TFR(15) TFR(26) TFR(6)   x0 += k2; x1 += k0 + 5u;
#undef TFR
  o0 = x0; o1 = x1;
}

__device__ __forceinline__ float pe_val(int n, int c) {
  int dd = n % 24, ww = (n / 24) % 24, hh = n / 576;
  if (c == 126)
    return sinf((float)hh) + sinf(0.01f * (float)ww) + sinf(0.0001f * (float)dd);
  return cosf((float)hh) + cosf(0.01f * (float)ww) + cosf(0.0001f * (float)dd);
}

// ---------------- packAll: 5 weights -> MFMA B-frag bf16 ----------------
__device__ __forceinline__ void packOne(const float* __restrict__ W, int K, int N,
                                        unsigned short* __restrict__ P, int f) {
  int KT = K >> 5;
  int lane = f & 63;
  int ft = f >> 6;
  int kt = ft % KT, nt = ft / KT;
  int col = nt * 16 + (lane & 15);
  int k0 = kt * 32 + (lane >> 4) * 8;
  uint32_t w[4];
  #pragma unroll
  for (int p = 0; p < 4; ++p) {
    uint32_t lo = f2bf(W[(size_t)(k0 + 2 * p) * N + col]);
    uint32_t hi = f2bf(W[(size_t)(k0 + 2 * p + 1) * N + col]);
    w[p] = lo | (hi << 16);
  }
  uint4 v; v.x = w[0]; v.y = w[1]; v.z = w[2]; v.w = w[3];
  ((uint4*)P)[f] = v;
}

__global__ __launch_bounds__(256) void packAll(
    const float* __restrict__ Wqkv, const float* __restrict__ Wout,
    const float* __restrict__ Wff1, const float* __restrict__ Wff2,
    const float* __restrict__ Whead,
    unsigned short* __restrict__ pQkv, unsigned short* __restrict__ pOut,
    unsigned short* __restrict__ pFF1, unsigned short* __restrict__ pFF2,
    unsigned short* __restrict__ pHead) {
  int f = blockIdx.x * 256 + threadIdx.x;
  if (f < 6144)        packOne(Wqkv, 128, 384, pQkv, f);
  else if (f < 8192)   packOne(Wout, 128, 128, pOut, f - 6144);
  else if (f < 16384)  packOne(Wff1, 128, 512, pFF1, f - 8192);
  else if (f < 24576)  packOne(Wff2, 512, 128, pFF2, f - 16384);
  else if (f < 26624)  packOne(Whead, 128, 128, pHead, f - 24576);
}

// ---------------- K1: pe + LN1 + qkv GEMM (step 0 only) ----------------
__global__ __launch_bounds__(256) void nca_k1(
    const float* __restrict__ x, const float* __restrict__ ln1s,
    const float* __restrict__ ln1b, const unsigned short* __restrict__ pQkv,
    __half* __restrict__ wqkv,
    const int* __restrict__ steps, int s) {
  if (s >= *steps) return;
  __shared__ float ly[16][132];
  __shared__ float lmean[16], lrstd[16];
  const int t = threadIdx.x;
  const int swz = (blockIdx.x & 7) * 108 + (blockIdx.x >> 3);  // XCD-contiguous
  const int base = swz * 16;
  #pragma unroll
  for (int i = 0; i < 8; ++i) {
    int idx = i * 256 + t;
    int r = idx >> 7, c = idx & 127;
    int n = base + r;
    ly[r][c] = (c < 126) ? x[(size_t)n * 128 + c] : pe_val(n, c);
  }
  __syncthreads();
  { int r = t >> 4, j = t & 15;
    float s1 = 0.f, s2 = 0.f;
    #pragma unroll
    for (int cc = 0; cc < 8; ++cc) { float v = ly[r][j * 8 + cc]; s1 += v; s2 += v * v; }
    #pragma unroll
    for (int off = 1; off < 16; off <<= 1) { s1 += __shfl_xor(s1, off); s2 += __shfl_xor(s2, off); }
    if (j == 0) {
      float m = s1 * (1.f / 128.f);
      float var = s2 * (1.f / 128.f) - m * m;
      lmean[r] = m; lrstd[r] = rsqrtf(var + 1e-5f);
    }
  }
  __syncthreads();
  #pragma unroll
  for (int i = 0; i < 8; ++i) {
    int idx = i * 256 + t;
    int r = idx >> 7, c = idx & 127;
    ly[r][c] = (ly[r][c] - lmean[r]) * lrstd[r] * ln1s[c] + ln1b[c];
  }
  __syncthreads();
  const int w = t >> 6, l = t & 63;
  bf16x8 a4[4];
  #pragma unroll
  for (int kt = 0; kt < 4; ++kt)
    a4[kt] = afrag_f32(&ly[l & 15][kt * 32 + (l >> 4) * 8]);
  const bf16x8* B = (const bf16x8*)pQkv;
  #pragma unroll
  for (int q = 0; q < 6; ++q) {
    f32x4 acc = (f32x4){0.f, 0.f, 0.f, 0.f};
    int nt = w * 6 + q;
    #pragma unroll
    for (int kt = 0; kt < 4; ++kt)
      acc = __builtin_amdgcn_mfma_f32_16x16x32_bf16(a4[kt], B[(nt * 4 + kt) * 64 + l], acc, 0, 0, 0);
    int col = nt * 16 + (l & 15);
    #pragma unroll
    for (int j = 0; j < 4; ++j)
      wqkv[(size_t)(base + (l >> 4) * 4 + j) * 384 + col] = __float2half(acc[j]);
  }
}

// ---- kA: attn + out-proj + LN2 + FF1 + FF2 + LN3 + head + mask-update + next qkv ----
__global__ __launch_bounds__(512, 4) void nca_kA(
    const __half* __restrict__ qkv, __half* __restrict__ qkvN,
    const unsigned short* __restrict__ pQkv,
    const unsigned short* __restrict__ pOut, const float* __restrict__ bout,
    const float* __restrict__ ln1s, const float* __restrict__ ln1b,
    const float* __restrict__ ln2s, const float* __restrict__ ln2b,
    const unsigned short* __restrict__ pFF1, const float* __restrict__ bff1,
    const unsigned short* __restrict__ pFF2, const float* __restrict__ bff2,
    const float* __restrict__ ln3s, const float* __restrict__ ln3b,
    const unsigned short* __restrict__ pHead, const float* __restrict__ bhead,
    const float* __restrict__ xin, float* __restrict__ xout,
    const int* __restrict__ steps, int s) {
  if (s >= *steps) return;
  __shared__ unsigned short lnorm[16][136];  // bf16: attn-out / ln2 / ln3 / ln1'
  __shared__ float ly2[16][132];             // f32: y2 -> y3 (in place) -> x_new
  __shared__ unsigned short lh[16][520];     // bf16: GELU(FF1)
  __shared__ float lmask[16];
  const int t = threadIdx.x;
  const int swz = (blockIdx.x & 7) * 108 + (blockIdx.x >> 3);  // XCD-contiguous
  const int base = swz * 16;
  const int w = t >> 6, l = t & 63;
  const int lr = (l >> 4) * 4, lc = l & 15;

  if (t < 16) { // JAX threefry per-cell mask (partitionable random_bits)
    uint32_t kk0, kk1, b0, b1;
    tf2x32(0u, 42u, 0u, (uint32_t)s, kk0, kk1);
    tf2x32(kk0, kk1, 0u, (uint32_t)(base + t), b0, b1);
    uint32_t bits = b0 ^ b1;
    lmask[t] = ((bits >> 9) > 0x400000u) ? 1.0f : 0.0f;
  }
  // ---- attention: 16 cells x 8 heads x 4 quarters = 512 threads ----
  // single fused loop: K-dot + exp (no max-sub; |logit|<~2) + PV, unnormalized
  {
    const int cell = t >> 5, head = (t >> 2) & 7, qr = t & 3;
    const int n = base + cell;
    const int dd = n % 24, ww = (n / 24) % 24, hh = n / 576;
    __half2 q0, q1;
    ldh2x2(qkv + (size_t)n * 384 + head * 16 + qr * 4, q0, q1);
    const __half* kc = qkv + (size_t)n * 384 + 128 + head * 16 + qr * 4;
    const __half2 hz = __float2half2_rn(0.f);
    float den = 0.f;
    __half2 av0 = hz, av1 = hz;
    #pragma unroll
    for (int di = -1; di <= 1; ++di)
    #pragma unroll
    for (int dj = -1; dj <= 1; ++dj)
    #pragma unroll
    for (int dk = -1; dk <= 1; ++dk) {
      bool ok = ((unsigned)(hh + di) < 24u) && ((unsigned)(ww + dj) < 24u) &&
                ((unsigned)(dd + dk) < 24u);
      float dot = 0.f;
      __half2 v0 = hz, v1 = hz;
      if (ok) {
        const __half* kp = kc + (di * 576 + dj * 24 + dk) * 384;
        __half2 k0, k1;
        ldh2x2(kp, k0, k1);
        ldh2x2(kp + 128, v0, v1);          // V row (independent load, issues early)
        __half2 d2 = __hfma2(q0, k0, __hfma2(q1, k1, hz));
        dot = __low2float(d2) + __high2float(d2);
      }
      dot += __shfl_xor(dot, 1);
      dot += __shfl_xor(dot, 2);           // full 16-ch dot in all 4 lanes
      float e = __expf(dot * 0.25f);       // OOB -> dot 0 -> e = 1 (zero-pad softmax)
      den += e;
      __half2 e2 = __float2half2_rn(e);
      av0 = __hfma2(e2, v0, av0);          // OOB v = 0 contributes nothing
      av1 = __hfma2(e2, v1, av1);
    }
    float inv = 1.f / den;
    float2 f0 = __half22float2(av0), f1 = __half22float2(av1);
    uint32_t w0 = (uint32_t)f2bf(f0.x * inv) | ((uint32_t)f2bf(f0.y * inv) << 16);
    uint32_t w1 = (uint32_t)f2bf(f1.x * inv) | ((uint32_t)f2bf(f1.y * inv) << 16);
    *(uint2*)&lnorm[cell][head * 16 + qr * 4] = (uint2){w0, w1};
  }
  __syncthreads();
  // ---- out-proj: wave w -> coltile w; epilogue y2 -> ly2 (f32) ----
  bf16x8 a4[4];
  #pragma unroll
  for (int kt = 0; kt < 4; ++kt)
    a4[kt] = *(const bf16x8*)&lnorm[l & 15][kt * 32 + (l >> 4) * 8];
  float xres[4];
  {
    f32x4 acc = (f32x4){0.f,0.f,0.f,0.f};
    const bf16x8* B = (const bf16x8*)pOut;
    #pragma unroll
    for (int kt = 0; kt < 4; ++kt)
      acc = __builtin_amdgcn_mfma_f32_16x16x32_bf16(a4[kt], B[(w * 4 + kt) * 64 + l], acc, 0, 0, 0);
    int col = w * 16 + lc;
    #pragma unroll
    for (int j = 0; j < 4; ++j) {
      int r = lr + j, n = base + r;
      xres[j] = xin[(size_t)n * 128 + col];                 // true x (for final update)
      float resy = (col < 126) ? xres[j] : pe_val(n, col);  // y residual has pe
      ly2[r][col] = acc[j] + bout[col] + resy;
    }
  }
  __syncthreads();
  { // ---- LN2: butterfly stats + normalize own 4 ch -> lnorm bf16 ----
    int r = t >> 5, j = t & 31;
    float v0 = ly2[r][j*4], v1 = ly2[r][j*4+1], v2 = ly2[r][j*4+2], v3 = ly2[r][j*4+3];
    float s1 = v0 + v1 + v2 + v3;
    float s2 = v0*v0 + v1*v1 + v2*v2 + v3*v3;
    #pragma unroll
    for (int off = 1; off < 32; off <<= 1) { s1 += __shfl_xor(s1, off); s2 += __shfl_xor(s2, off); }
    float m = s1 * (1.f / 128.f);
    float rstd = rsqrtf(s2 * (1.f / 128.f) - m * m + 1e-5f);
    float n0 = (v0 - m) * rstd * ln2s[j*4]   + ln2b[j*4];
    float n1 = (v1 - m) * rstd * ln2s[j*4+1] + ln2b[j*4+1];
    float n2 = (v2 - m) * rstd * ln2s[j*4+2] + ln2b[j*4+2];
    float n3 = (v3 - m) * rstd * ln2s[j*4+3] + ln2b[j*4+3];
    uint32_t w0 = (uint32_t)f2bf(n0) | ((uint32_t)f2bf(n1) << 16);
    uint32_t w1 = (uint32_t)f2bf(n2) | ((uint32_t)f2bf(n3) << 16);
    *(uint2*)&lnorm[r][j * 4] = (uint2){w0, w1};
  }
  __syncthreads();
  // ---- FF1: wave w -> coltiles w*4..w*4+3; fast GELU -> lh bf16 ----
  #pragma unroll
  for (int kt = 0; kt < 4; ++kt)
    a4[kt] = *(const bf16x8*)&lnorm[l & 15][kt * 32 + (l >> 4) * 8];
  {
    f32x4 acc[4];
    #pragma unroll
    for (int q = 0; q < 4; ++q) acc[q] = (f32x4){0.f,0.f,0.f,0.f};
    const bf16x8* B = (const bf16x8*)pFF1;
    #pragma unroll
    for (int kt = 0; kt < 4; ++kt) {
      #pragma unroll
      for (int q = 0; q < 4; ++q) {
        int nt = w * 4 + q;
        acc[q] = __builtin_amdgcn_mfma_f32_16x16x32_bf16(a4[kt], B[(nt * 4 + kt) * 64 + l], acc[q], 0, 0, 0);
      }
    }
    #pragma unroll
    for (int q = 0; q < 4; ++q) {
      int col = (w * 4 + q) * 16 + lc;
      #pragma unroll
      for (int j = 0; j < 4; ++j)
        lh[lr + j][col] = f2bf(gelu_f(acc[q][j] + bff1[col]));
    }
  }
  __syncthreads();
  // ---- FF2: K=512, wave w -> coltile w; y3 = acc + b + y2 in place (owner) ----
  {
    f32x4 acc = (f32x4){0.f,0.f,0.f,0.f};
    const bf16x8* B = (const bf16x8*)pFF2;
    #pragma unroll
    for (int kt = 0; kt < 16; ++kt) {
      bf16x8 a = *(const bf16x8*)&lh[l & 15][kt * 32 + (l >> 4) * 8];
      acc = __builtin_amdgcn_mfma_f32_16x16x32_bf16(a, B[(w * 16 + kt) * 64 + l], acc, 0, 0, 0);
    }
    int col = w * 16 + lc;
    #pragma unroll
    for (int j = 0; j < 4; ++j) {
      int r = lr + j;
      ly2[r][col] = acc[j] + bff2[col] + ly2[r][col];
    }
  }
  __syncthreads();
  { // ---- LN3: butterfly stats + normalize -> lnorm bf16 ----
    int r = t >> 5, j = t & 31;
    float v0 = ly2[r][j*4], v1 = ly2[r][j*4+1], v2 = ly2[r][j*4+2], v3 = ly2[r][j*4+3];
    float s1 = v0 + v1 + v2 + v3;
    float s2 = v0*v0 + v1*v1 + v2*v2 + v3*v3;
    #pragma unroll
    for (int off = 1; off < 32; off <<= 1) { s1 += __shfl_xor(s1, off); s2 += __shfl_xor(s2, off); }
    float m = s1 * (1.f / 128.f);
    float rstd = rsqrtf(s2 * (1.f / 128.f) - m * m + 1e-5f);
    float n0 = (v0 - m) * rstd * ln3s[j*4]   + ln3b[j*4];
    float n1 = (v1 - m) * rstd * ln3s[j*4+1] + ln3b[j*4+1];
    float n2 = (v2 - m) * rstd * ln3s[j*4+2] + ln3b[j*4+2];
    float n3 = (v3 - m) * rstd * ln3s[j*4+3] + ln3b[j*4+3];
    uint32_t w0 = (uint32_t)f2bf(n0) | ((uint32_t)f2bf(n1) << 16);
    uint32_t w1 = (uint32_t)f2bf(n2) | ((uint32_t)f2bf(n3) << 16);
    *(uint2*)&lnorm[r][j * 4] = (uint2){w0, w1};
  }
  __syncthreads();
  // ---- head: wave w -> coltile w; dx; masked update; x_new -> ly2 ----
  #pragma unroll
  for (int kt = 0; kt < 4; ++kt)
    a4[kt] = *(const bf16x8*)&lnorm[l & 15][kt * 32 + (l >> 4) * 8];
  {
    f32x4 acc = (f32x4){0.f,0.f,0.f,0.f};
    const bf16x8* B = (const bf16x8*)pHead;
    #pragma unroll
    for (int kt = 0; kt < 4; ++kt)
      acc = __builtin_amdgcn_mfma_f32_16x16x32_bf16(a4[kt], B[(w * 4 + kt) * 64 + l], acc, 0, 0, 0);
    int col = w * 16 + lc;
    #pragma unroll
    for (int j = 0; j < 4; ++j) {
      int r = lr + j;
      size_t n = base + r;
      float dx = acc[j] + bhead[col];
      float xn = xres[j] + dx * lmask[r];
      xout[n * 128 + col] = xn;
      ly2[r][col] = xn;
    }
  }
  // ---- tail: next step's pe + LN1 + qkv GEMM (skipped on last step) ----
  if (s + 1 < *steps) {
    __syncthreads();
    if (t < 32) { int r = t >> 1, c = 126 + (t & 1); ly2[r][c] = pe_val(base + r, c); }
    __syncthreads();
    { // LN1: butterfly stats + normalize -> lnorm bf16
      int r = t >> 5, j = t & 31;
      float v0 = ly2[r][j*4], v1 = ly2[r][j*4+1], v2 = ly2[r][j*4+2], v3 = ly2[r][j*4+3];
      float s1 = v0 + v1 + v2 + v3;
      float s2 = v0*v0 + v1*v1 + v2*v2 + v3*v3;
      #pragma unroll
      for (int off = 1; off < 32; off <<= 1) { s1 += __shfl_xor(s1, off); s2 += __shfl_xor(s2, off); }
      float m = s1 * (1.f / 128.f);
      float rstd = rsqrtf(s2 * (1.f / 128.f) - m * m + 1e-5f);
      float n0 = (v0 - m) * rstd * ln1s[j*4]   + ln1b[j*4];
      float n1 = (v1 - m) * rstd * ln1s[j*4+1] + ln1b[j*4+1];
      float n2 = (v2 - m) * rstd * ln1s[j*4+2] + ln1b[j*4+2];
      float n3 = (v3 - m) * rstd * ln1s[j*4+3] + ln1b[j*4+3];
      uint32_t w0 = (uint32_t)f2bf(n0) | ((uint32_t)f2bf(n1) << 16);
      uint32_t w1 = (uint32_t)f2bf(n2) | ((uint32_t)f2bf(n3) << 16);
      *(uint2*)&lnorm[r][j * 4] = (uint2){w0, w1};
    }
    __syncthreads();
    #pragma unroll
    for (int kt = 0; kt < 4; ++kt)
      a4[kt] = *(const bf16x8*)&lnorm[l & 15][kt * 32 + (l >> 4) * 8];
    const bf16x8* B = (const bf16x8*)pQkv;
    #pragma unroll
    for (int q = 0; q < 3; ++q) {
      f32x4 acc = (f32x4){0.f,0.f,0.f,0.f};
      int nt = w * 3 + q;
      #pragma unroll
      for (int kt = 0; kt < 4; ++kt)
        acc = __builtin_amdgcn_mfma_f32_16x16x32_bf16(a4[kt], B[(nt * 4 + kt) * 64 + l], acc, 0, 0, 0);
      int col = nt * 16 + lc;
      #pragma unroll
      for (int j = 0; j < 4; ++j)
        qkvN[(size_t)(base + lr + j) * 384 + col] = __float2half(acc[j]);
    }
  }
}

extern "C" void kernel_launch(void* const* d_in, const int* in_sizes, int n_in,
                              void* d_out, int out_size, void* d_ws, size_t ws_size,
                              hipStream_t stream) {
  const float* x0   = (const float*)d_in[0];
  const float* Wqkv = (const float*)d_in[1];
  const float* Wout = (const float*)d_in[2];
  const float* bout = (const float*)d_in[3];
  const float* ln1s = (const float*)d_in[4];
  const float* ln1b = (const float*)d_in[5];
  const float* Wff1 = (const float*)d_in[6];
  const float* bff1 = (const float*)d_in[7];
  const float* Wff2 = (const float*)d_in[8];
  const float* bff2 = (const float*)d_in[9];
  const float* ln2s = (const float*)d_in[10];
  const float* ln2b = (const float*)d_in[11];
  const float* ln3s = (const float*)d_in[12];
  const float* ln3b = (const float*)d_in[13];
  const float* Whead= (const float*)d_in[14];
  const float* bhead= (const float*)d_in[15];
  const int*   steps= (const int*)d_in[16];
  float* out = (float*)d_out;

  __half* qkvA = (__half*)d_ws;                          // N*384 f16
  __half* qkvB = qkvA + (size_t)NCELL * 384;             // N*384 f16
  unsigned short* pQkv = (unsigned short*)(qkvB + (size_t)NCELL * 384);
  unsigned short* pOut = pQkv + 128 * 384;
  unsigned short* pFF1 = pOut + 128 * 128;
  unsigned short* pFF2 = pFF1 + 128 * 512;
  unsigned short* pHead= pFF2 + 512 * 128;

  packAll<<<dim3(104), dim3(256), 0, stream>>>(Wqkv, Wout, Wff1, Wff2, Whead,
                                               pQkv, pOut, pFF1, pFF2, pHead);
  nca_k1<<<dim3(864), dim3(256), 0, stream>>>(x0, ln1s, ln1b, pQkv, qkvA, steps, 0);
  // s=0: read qkvA, write next-step qkvB; s=1: read qkvB (tail skipped)
  nca_kA<<<dim3(864), dim3(512), 0, stream>>>(qkvA, qkvB, pQkv, pOut, bout,
                                              ln1s, ln1b, ln2s, ln2b, pFF1, bff1,
                                              pFF2, bff2, ln3s, ln3b, pHead, bhead,
                                              x0, out, steps, 0);
  nca_kA<<<dim3(864), dim3(512), 0, stream>>>(qkvB, qkvA, pQkv, pOut, bout,
                                              ln1s, ln1b, ln2s, ln2b, pFF1, bff1,
                                              pFF2, bff2, ln3s, ln3b, pHead, bhead,
                                              out, out, steps, 1);
}

// Round 9
// 104.209 us; speedup vs baseline: 1.4594x; 1.1072x over previous
//
#include <hip/hip_runtime.h>
#include <hip/hip_fp16.h>
#include <cstdint>
#include <cstddef>

// BasicViTNCA3D: 24^3 cells, C=128, 8 heads x dim16, MLP 512, 2 NCA steps.
// R9 = R8 + attention load restructure:
//  - clamped neighbor addressing -> ALL K/V loads unconditional (hoistable batch);
//    OOB handled arithmetically (dot masked to 0 -> e=1 in den; PV weight masked to 0)
//  - v_dot2_f32_f16 for QK dots (guarded, hfma2 fallback)
//  - xin residual (xres) prefetched at kernel entry (was on post-barrier critical path)
#define NCELL 13824

typedef short bf16x8 __attribute__((ext_vector_type(8)));  // 8 bf16 (4 VGPRs)
typedef float f32x4  __attribute__((ext_vector_type(4)));  // MFMA acc
typedef _Float16 h2v __attribute__((ext_vector_type(2)));

__device__ __forceinline__ unsigned short f2bf(float x) {
  union { float f; uint32_t u; } c; c.f = x;
  uint32_t r = c.u + 0x7fffu + ((c.u >> 16) & 1u);  // RNE
  return (unsigned short)(r >> 16);
}

// A-fragment (16x32 tile, row = lane&15, k = (lane>>4)*8+j) from fp32 LDS row
__device__ __forceinline__ bf16x8 afrag_f32(const float* p) {
  float4 u0 = *(const float4*)p;
  float4 u1 = *(const float4*)(p + 4);
  bf16x8 a;
  a[0] = (short)f2bf(u0.x); a[1] = (short)f2bf(u0.y);
  a[2] = (short)f2bf(u0.z); a[3] = (short)f2bf(u0.w);
  a[4] = (short)f2bf(u1.x); a[5] = (short)f2bf(u1.y);
  a[6] = (short)f2bf(u1.z); a[7] = (short)f2bf(u1.w);
  return a;
}

// load 2x __half2 (8B) from f16 pointer
__device__ __forceinline__ void ldh2x2(const __half* p, __half2& a, __half2& b) {
  uint2 u = *(const uint2*)p;
  union { uint32_t u; __half2 h; } c0, c1;
  c0.u = u.x; c1.u = u.y;
  a = c0.h; b = c1.h;
}

// f32 += dot(half2, half2) via v_dot2_f32_f16 when available
__device__ __forceinline__ float fdot2(__half2 a, __half2 b, float c) {
#if __has_builtin(__builtin_amdgcn_fdot2)
  union { __half2 h; h2v n; } ua, ub;
  ua.h = a; ub.h = b;
  return __builtin_amdgcn_fdot2(ua.n, ub.n, c, false);
#else
  __half2 d = __hmul2(a, b);
  return c + __low2float(d) + __high2float(d);
#endif
}

// inf-safe tanh-form GELU (max abs dev ~1e-3 vs exact erf GELU)
__device__ __forceinline__ float gelu_f(float x) {
  float u = 0.7978845608f * x * (1.f + 0.044715f * x * x);
  float e = __expf(2.f * u);
  float t = 1.f - 2.f / (e + 1.f);   // tanh(u)
  return 0.5f * x * (1.f + t);
}

// ---------------- Threefry-2x32 (JAX-compatible) ----------------
__device__ __forceinline__ void tf2x32(uint32_t k0, uint32_t k1,
                                       uint32_t x0, uint32_t x1,
                                       uint32_t& o0, uint32_t& o1) {
  uint32_t k2 = k0 ^ k1 ^ 0x1BD11BDAu;
  x0 += k0; x1 += k1;
#define TFR(r) { x0 += x1; x1 = (x1 << (r)) | (x1 >> (32 - (r))); x1 ^= x0; }
  TFR(13) TFR(15) TFR(26) TFR(6)   x0 += k1; x1 += k2 + 1u;
  TFR(17) TFR(29) TFR(16) TFR(24)  x0 += k2; x1 += k0 + 2u;
  TFR(13) TFR(15) TFR(26) TFR(6)   x0 += k0; x1 += k1 + 3u;
  TFR(17) TFR(29) TFR(16) TFR(24)  x0 += k1; x1 += k2 + 4u;
  TFR(13) TFR(15) TFR(26) TFR(6)   x0 += k2; x1 += k0 + 5u;
#undef TFR
  o0 = x0; o1 = x1;
}

__device__ __forceinline__ float pe_val(int n, int c) {
  int dd = n % 24, ww = (n / 24) % 24, hh = n / 576;
  if (c == 126)
    return sinf((float)hh) + sinf(0.01f * (float)ww) + sinf(0.0001f * (float)dd);
  return cosf((float)hh) + cosf(0.01f * (float)ww) + cosf(0.0001f * (float)dd);
}

// ---------------- packAll: 5 weights -> MFMA B-frag bf16 ----------------
__device__ __forceinline__ void packOne(const float* __restrict__ W, int K, int N,
                                        unsigned short* __restrict__ P, int f) {
  int KT = K >> 5;
  int lane = f & 63;
  int ft = f >> 6;
  int kt = ft % KT, nt = ft / KT;
  int col = nt * 16 + (lane & 15);
  int k0 = kt * 32 + (lane >> 4) * 8;
  uint32_t w[4];
  #pragma unroll
  for (int p = 0; p < 4; ++p) {
    uint32_t lo = f2bf(W[(size_t)(k0 + 2 * p) * N + col]);
    uint32_t hi = f2bf(W[(size_t)(k0 + 2 * p + 1) * N + col]);
    w[p] = lo | (hi << 16);
  }
  uint4 v; v.x = w[0]; v.y = w[1]; v.z = w[2]; v.w = w[3];
  ((uint4*)P)[f] = v;
}

__global__ __launch_bounds__(256) void packAll(
    const float* __restrict__ Wqkv, const float* __restrict__ Wout,
    const float* __restrict__ Wff1, const float* __restrict__ Wff2,
    const float* __restrict__ Whead,
    unsigned short* __restrict__ pQkv, unsigned short* __restrict__ pOut,
    unsigned short* __restrict__ pFF1, unsigned short* __restrict__ pFF2,
    unsigned short* __restrict__ pHead) {
  int f = blockIdx.x * 256 + threadIdx.x;
  if (f < 6144)        packOne(Wqkv, 128, 384, pQkv, f);
  else if (f < 8192)   packOne(Wout, 128, 128, pOut, f - 6144);
  else if (f < 16384)  packOne(Wff1, 128, 512, pFF1, f - 8192);
  else if (f < 24576)  packOne(Wff2, 512, 128, pFF2, f - 16384);
  else if (f < 26624)  packOne(Whead, 128, 128, pHead, f - 24576);
}

// ---------------- K1: pe + LN1 + qkv GEMM (step 0 only) ----------------
__global__ __launch_bounds__(256) void nca_k1(
    const float* __restrict__ x, const float* __restrict__ ln1s,
    const float* __restrict__ ln1b, const unsigned short* __restrict__ pQkv,
    __half* __restrict__ wqkv,
    const int* __restrict__ steps, int s) {
  if (s >= *steps) return;
  __shared__ float ly[16][132];
  __shared__ float lmean[16], lrstd[16];
  const int t = threadIdx.x;
  const int swz = (blockIdx.x & 7) * 108 + (blockIdx.x >> 3);  // XCD-contiguous
  const int base = swz * 16;
  #pragma unroll
  for (int i = 0; i < 8; ++i) {
    int idx = i * 256 + t;
    int r = idx >> 7, c = idx & 127;
    int n = base + r;
    ly[r][c] = (c < 126) ? x[(size_t)n * 128 + c] : pe_val(n, c);
  }
  __syncthreads();
  { int r = t >> 4, j = t & 15;
    float s1 = 0.f, s2 = 0.f;
    #pragma unroll
    for (int cc = 0; cc < 8; ++cc) { float v = ly[r][j * 8 + cc]; s1 += v; s2 += v * v; }
    #pragma unroll
    for (int off = 1; off < 16; off <<= 1) { s1 += __shfl_xor(s1, off); s2 += __shfl_xor(s2, off); }
    if (j == 0) {
      float m = s1 * (1.f / 128.f);
      float var = s2 * (1.f / 128.f) - m * m;
      lmean[r] = m; lrstd[r] = rsqrtf(var + 1e-5f);
    }
  }
  __syncthreads();
  #pragma unroll
  for (int i = 0; i < 8; ++i) {
    int idx = i * 256 + t;
    int r = idx >> 7, c = idx & 127;
    ly[r][c] = (ly[r][c] - lmean[r]) * lrstd[r] * ln1s[c] + ln1b[c];
  }
  __syncthreads();
  const int w = t >> 6, l = t & 63;
  bf16x8 a4[4];
  #pragma unroll
  for (int kt = 0; kt < 4; ++kt)
    a4[kt] = afrag_f32(&ly[l & 15][kt * 32 + (l >> 4) * 8]);
  const bf16x8* B = (const bf16x8*)pQkv;
  #pragma unroll
  for (int q = 0; q < 6; ++q) {
    f32x4 acc = (f32x4){0.f, 0.f, 0.f, 0.f};
    int nt = w * 6 + q;
    #pragma unroll
    for (int kt = 0; kt < 4; ++kt)
      acc = __builtin_amdgcn_mfma_f32_16x16x32_bf16(a4[kt], B[(nt * 4 + kt) * 64 + l], acc, 0, 0, 0);
    int col = nt * 16 + (l & 15);
    #pragma unroll
    for (int j = 0; j < 4; ++j)
      wqkv[(size_t)(base + (l >> 4) * 4 + j) * 384 + col] = __float2half(acc[j]);
  }
}

// ---- kA: attn + out-proj + LN2 + FF1 + FF2 + LN3 + head + mask-update + next qkv ----
__global__ __launch_bounds__(512, 4) void nca_kA(
    const __half* __restrict__ qkv, __half* __restrict__ qkvN,
    const unsigned short* __restrict__ pQkv,
    const unsigned short* __restrict__ pOut, const float* __restrict__ bout,
    const float* __restrict__ ln1s, const float* __restrict__ ln1b,
    const float* __restrict__ ln2s, const float* __restrict__ ln2b,
    const unsigned short* __restrict__ pFF1, const float* __restrict__ bff1,
    const unsigned short* __restrict__ pFF2, const float* __restrict__ bff2,
    const float* __restrict__ ln3s, const float* __restrict__ ln3b,
    const unsigned short* __restrict__ pHead, const float* __restrict__ bhead,
    const float* __restrict__ xin, float* __restrict__ xout,
    const int* __restrict__ steps, int s) {
  if (s >= *steps) return;
  __shared__ unsigned short lnorm[16][136];  // bf16: attn-out / ln2 / ln3 / ln1'
  __shared__ float ly2[16][132];             // f32: y2 -> y3 (in place) -> x_new
  __shared__ unsigned short lh[16][520];     // bf16: GELU(FF1)
  __shared__ float lmask[16];
  const int t = threadIdx.x;
  const int swz = (blockIdx.x & 7) * 108 + (blockIdx.x >> 3);  // XCD-contiguous
  const int base = swz * 16;
  const int w = t >> 6, l = t & 63;
  const int lr = (l >> 4) * 4, lc = l & 15;

  // prefetch residual x for this thread's GEMM output slots (consumed post-barrier)
  float xres[4];
  {
    int col = w * 16 + lc;
    #pragma unroll
    for (int j = 0; j < 4; ++j)
      xres[j] = xin[(size_t)(base + lr + j) * 128 + col];
  }
  if (t < 16) { // JAX threefry per-cell mask (partitionable random_bits)
    uint32_t kk0, kk1, b0, b1;
    tf2x32(0u, 42u, 0u, (uint32_t)s, kk0, kk1);
    tf2x32(kk0, kk1, 0u, (uint32_t)(base + t), b0, b1);
    uint32_t bits = b0 ^ b1;
    lmask[t] = ((bits >> 9) > 0x400000u) ? 1.0f : 0.0f;
  }
  // ---- attention: 16 cells x 8 heads x 4 quarters = 512 threads ----
  // fused loop, clamp-addressed unconditional loads, arithmetic OOB masking
  {
    const int cell = t >> 5, head = (t >> 2) & 7, qr = t & 3;
    const int n = base + cell;
    const int dd = n % 24, ww = (n / 24) % 24, hh = n / 576;
    const int qoff = head * 16 + qr * 4;
    __half2 q0, q1;
    ldh2x2(qkv + (size_t)n * 384 + qoff, q0, q1);
    const __half* kb = qkv + 128 + qoff;     // + nn*384 per neighbor
    const __half2 hz = __float2half2_rn(0.f);
    float den = 0.f;
    __half2 av0 = hz, av1 = hz;
    #pragma unroll
    for (int di = -1; di <= 1; ++di) {
      int hh2 = hh + di;
      bool okh = (unsigned)hh2 < 24u;
      int hc = min(max(hh2, 0), 23) * 576;
      #pragma unroll
      for (int dj = -1; dj <= 1; ++dj) {
        int ww2 = ww + dj;
        bool okw = okh && ((unsigned)ww2 < 24u);
        int wc = hc + min(max(ww2, 0), 23) * 24;
        #pragma unroll
        for (int dk = -1; dk <= 1; ++dk) {
          int dd2 = dd + dk;
          bool ok = okw && ((unsigned)dd2 < 24u);
          int nn = wc + min(max(dd2, 0), 23);
          const __half* kp = kb + (size_t)nn * 384;
          __half2 k0, k1, v0, v1;
          ldh2x2(kp, k0, k1);          // unconditional (clamped -> in range)
          ldh2x2(kp + 128, v0, v1);    // V row
          float dotc = fdot2(q1, k1, fdot2(q0, k0, 0.f));
          float dot = ok ? dotc : 0.f;
          dot += __shfl_xor(dot, 1);
          dot += __shfl_xor(dot, 2);   // full 16-ch dot in all 4 lanes
          float e = __expf(dot * 0.25f);  // OOB -> dot 0 -> e = 1 (zero-pad softmax)
          den += e;
          float em = ok ? e : 0.f;        // OOB contributes nothing to PV
          __half2 e2 = __float2half2_rn(em);
          av0 = __hfma2(e2, v0, av0);
          av1 = __hfma2(e2, v1, av1);
        }
      }
    }
    float inv = 1.f / den;
    float2 f0 = __half22float2(av0), f1 = __half22float2(av1);
    uint32_t w0 = (uint32_t)f2bf(f0.x * inv) | ((uint32_t)f2bf(f0.y * inv) << 16);
    uint32_t w1 = (uint32_t)f2bf(f1.x * inv) | ((uint32_t)f2bf(f1.y * inv) << 16);
    *(uint2*)&lnorm[cell][qoff] = (uint2){w0, w1};
  }
  __syncthreads();
  // ---- out-proj: wave w -> coltile w; epilogue y2 -> ly2 (f32) ----
  bf16x8 a4[4];
  #pragma unroll
  for (int kt = 0; kt < 4; ++kt)
    a4[kt] = *(const bf16x8*)&lnorm[l & 15][kt * 32 + (l >> 4) * 8];
  {
    f32x4 acc = (f32x4){0.f,0.f,0.f,0.f};
    const bf16x8* B = (const bf16x8*)pOut;
    #pragma unroll
    for (int kt = 0; kt < 4; ++kt)
      acc = __builtin_amdgcn_mfma_f32_16x16x32_bf16(a4[kt], B[(w * 4 + kt) * 64 + l], acc, 0, 0, 0);
    int col = w * 16 + lc;
    #pragma unroll
    for (int j = 0; j < 4; ++j) {
      int r = lr + j, n = base + r;
      float resy = (col < 126) ? xres[j] : pe_val(n, col);  // y residual has pe
      ly2[r][col] = acc[j] + bout[col] + resy;
    }
  }
  __syncthreads();
  { // ---- LN2: butterfly stats + normalize own 4 ch -> lnorm bf16 ----
    int r = t >> 5, j = t & 31;
    float v0 = ly2[r][j*4], v1 = ly2[r][j*4+1], v2 = ly2[r][j*4+2], v3 = ly2[r][j*4+3];
    float s1 = v0 + v1 + v2 + v3;
    float s2 = v0*v0 + v1*v1 + v2*v2 + v3*v3;
    #pragma unroll
    for (int off = 1; off < 32; off <<= 1) { s1 += __shfl_xor(s1, off); s2 += __shfl_xor(s2, off); }
    float m = s1 * (1.f / 128.f);
    float rstd = rsqrtf(s2 * (1.f / 128.f) - m * m + 1e-5f);
    float n0 = (v0 - m) * rstd * ln2s[j*4]   + ln2b[j*4];
    float n1 = (v1 - m) * rstd * ln2s[j*4+1] + ln2b[j*4+1];
    float n2 = (v2 - m) * rstd * ln2s[j*4+2] + ln2b[j*4+2];
    float n3 = (v3 - m) * rstd * ln2s[j*4+3] + ln2b[j*4+3];
    uint32_t w0 = (uint32_t)f2bf(n0) | ((uint32_t)f2bf(n1) << 16);
    uint32_t w1 = (uint32_t)f2bf(n2) | ((uint32_t)f2bf(n3) << 16);
    *(uint2*)&lnorm[r][j * 4] = (uint2){w0, w1};
  }
  __syncthreads();
  // ---- FF1: wave w -> coltiles w*4..w*4+3; fast GELU -> lh bf16 ----
  #pragma unroll
  for (int kt = 0; kt < 4; ++kt)
    a4[kt] = *(const bf16x8*)&lnorm[l & 15][kt * 32 + (l >> 4) * 8];
  {
    f32x4 acc[4];
    #pragma unroll
    for (int q = 0; q < 4; ++q) acc[q] = (f32x4){0.f,0.f,0.f,0.f};
    const bf16x8* B = (const bf16x8*)pFF1;
    #pragma unroll
    for (int kt = 0; kt < 4; ++kt) {
      #pragma unroll
      for (int q = 0; q < 4; ++q) {
        int nt = w * 4 + q;
        acc[q] = __builtin_amdgcn_mfma_f32_16x16x32_bf16(a4[kt], B[(nt * 4 + kt) * 64 + l], acc[q], 0, 0, 0);
      }
    }
    #pragma unroll
    for (int q = 0; q < 4; ++q) {
      int col = (w * 4 + q) * 16 + lc;
      #pragma unroll
      for (int j = 0; j < 4; ++j)
        lh[lr + j][col] = f2bf(gelu_f(acc[q][j] + bff1[col]));
    }
  }
  __syncthreads();
  // ---- FF2: K=512, wave w -> coltile w; y3 = acc + b + y2 in place (owner) ----
  {
    f32x4 acc = (f32x4){0.f,0.f,0.f,0.f};
    const bf16x8* B = (const bf16x8*)pFF2;
    #pragma unroll
    for (int kt = 0; kt < 16; ++kt) {
      bf16x8 a = *(const bf16x8*)&lh[l & 15][kt * 32 + (l >> 4) * 8];
      acc = __builtin_amdgcn_mfma_f32_16x16x32_bf16(a, B[(w * 16 + kt) * 64 + l], acc, 0, 0, 0);
    }
    int col = w * 16 + lc;
    #pragma unroll
    for (int j = 0; j < 4; ++j) {
      int r = lr + j;
      ly2[r][col] = acc[j] + bff2[col] + ly2[r][col];
    }
  }
  __syncthreads();
  { // ---- LN3: butterfly stats + normalize -> lnorm bf16 ----
    int r = t >> 5, j = t & 31;
    float v0 = ly2[r][j*4], v1 = ly2[r][j*4+1], v2 = ly2[r][j*4+2], v3 = ly2[r][j*4+3];
    float s1 = v0 + v1 + v2 + v3;
    float s2 = v0*v0 + v1*v1 + v2*v2 + v3*v3;
    #pragma unroll
    for (int off = 1; off < 32; off <<= 1) { s1 += __shfl_xor(s1, off); s2 += __shfl_xor(s2, off); }
    float m = s1 * (1.f / 128.f);
    float rstd = rsqrtf(s2 * (1.f / 128.f) - m * m + 1e-5f);
    float n0 = (v0 - m) * rstd * ln3s[j*4]   + ln3b[j*4];
    float n1 = (v1 - m) * rstd * ln3s[j*4+1] + ln3b[j*4+1];
    float n2 = (v2 - m) * rstd * ln3s[j*4+2] + ln3b[j*4+2];
    float n3 = (v3 - m) * rstd * ln3s[j*4+3] + ln3b[j*4+3];
    uint32_t w0 = (uint32_t)f2bf(n0) | ((uint32_t)f2bf(n1) << 16);
    uint32_t w1 = (uint32_t)f2bf(n2) | ((uint32_t)f2bf(n3) << 16);
    *(uint2*)&lnorm[r][j * 4] = (uint2){w0, w1};
  }
  __syncthreads();
  // ---- head: wave w -> coltile w; dx; masked update; x_new -> ly2 ----
  #pragma unroll
  for (int kt = 0; kt < 4; ++kt)
    a4[kt] = *(const bf16x8*)&lnorm[l & 15][kt * 32 + (l >> 4) * 8];
  {
    f32x4 acc = (f32x4){0.f,0.f,0.f,0.f};
    const bf16x8* B = (const bf16x8*)pHead;
    #pragma unroll
    for (int kt = 0; kt < 4; ++kt)
      acc = __builtin_amdgcn_mfma_f32_16x16x32_bf16(a4[kt], B[(w * 4 + kt) * 64 + l], acc, 0, 0, 0);
    int col = w * 16 + lc;
    #pragma unroll
    for (int j = 0; j < 4; ++j) {
      int r = lr + j;
      size_t n = base + r;
      float dx = acc[j] + bhead[col];
      float xn = xres[j] + dx * lmask[r];
      xout[n * 128 + col] = xn;
      ly2[r][col] = xn;
    }
  }
  // ---- tail: next step's pe + LN1 + qkv GEMM (skipped on last step) ----
  if (s + 1 < *steps) {
    __syncthreads();
    if (t < 32) { int r = t >> 1, c = 126 + (t & 1); ly2[r][c] = pe_val(base + r, c); }
    __syncthreads();
    { // LN1: butterfly stats + normalize -> lnorm bf16
      int r = t >> 5, j = t & 31;
      float v0 = ly2[r][j*4], v1 = ly2[r][j*4+1], v2 = ly2[r][j*4+2], v3 = ly2[r][j*4+3];
      float s1 = v0 + v1 + v2 + v3;
      float s2 = v0*v0 + v1*v1 + v2*v2 + v3*v3;
      #pragma unroll
      for (int off = 1; off < 32; off <<= 1) { s1 += __shfl_xor(s1, off); s2 += __shfl_xor(s2, off); }
      float m = s1 * (1.f / 128.f);
      float rstd = rsqrtf(s2 * (1.f / 128.f) - m * m + 1e-5f);
      float n0 = (v0 - m) * rstd * ln1s[j*4]   + ln1b[j*4];
      float n1 = (v1 - m) * rstd * ln1s[j*4+1] + ln1b[j*4+1];
      float n2 = (v2 - m) * rstd * ln1s[j*4+2] + ln1b[j*4+2];
      float n3 = (v3 - m) * rstd * ln1s[j*4+3] + ln1b[j*4+3];
      uint32_t w0 = (uint32_t)f2bf(n0) | ((uint32_t)f2bf(n1) << 16);
      uint32_t w1 = (uint32_t)f2bf(n2) | ((uint32_t)f2bf(n3) << 16);
      *(uint2*)&lnorm[r][j * 4] = (uint2){w0, w1};
    }
    __syncthreads();
    #pragma unroll
    for (int kt = 0; kt < 4; ++kt)
      a4[kt] = *(const bf16x8*)&lnorm[l & 15][kt * 32 + (l >> 4) * 8];
    const bf16x8* B = (const bf16x8*)pQkv;
    #pragma unroll
    for (int q = 0; q < 3; ++q) {
      f32x4 acc = (f32x4){0.f,0.f,0.f,0.f};
      int nt = w * 3 + q;
      #pragma unroll
      for (int kt = 0; kt < 4; ++kt)
        acc = __builtin_amdgcn_mfma_f32_16x16x32_bf16(a4[kt], B[(nt * 4 + kt) * 64 + l], acc, 0, 0, 0);
      int col = nt * 16 + lc;
      #pragma unroll
      for (int j = 0; j < 4; ++j)
        qkvN[(size_t)(base + lr + j) * 384 + col] = __float2half(acc[j]);
    }
  }
}

extern "C" void kernel_launch(void* const* d_in, const int* in_sizes, int n_in,
                              void* d_out, int out_size, void* d_ws, size_t ws_size,
                              hipStream_t stream) {
  const float* x0   = (const float*)d_in[0];
  const float* Wqkv = (const float*)d_in[1];
  const float* Wout = (const float*)d_in[2];
  const float* bout = (const float*)d_in[3];
  const float* ln1s = (const float*)d_in[4];
  const float* ln1b = (const float*)d_in[5];
  const float* Wff1 = (const float*)d_in[6];
  const float* bff1 = (const float*)d_in[7];
  const float* Wff2 = (const float*)d_in[8];
  const float* bff2 = (const float*)d_in[9];
  const float* ln2s = (const float*)d_in[10];
  const float* ln2b = (const float*)d_in[11];
  const float* ln3s = (const float*)d_in[12];
  const float* ln3b = (const float*)d_in[13];
  const float* Whead= (const float*)d_in[14];
  const float* bhead= (const float*)d_in[15];
  const int*   steps= (const int*)d_in[16];
  float* out = (float*)d_out;

  __half* qkvA = (__half*)d_ws;                          // N*384 f16
  __half* qkvB = qkvA + (size_t)NCELL * 384;             // N*384 f16
  unsigned short* pQkv = (unsigned short*)(qkvB + (size_t)NCELL * 384);
  unsigned short* pOut = pQkv + 128 * 384;
  unsigned short* pFF1 = pOut + 128 * 128;
  unsigned short* pFF2 = pFF1 + 128 * 512;
  unsigned short* pHead= pFF2 + 512 * 128;

  packAll<<<dim3(104), dim3(256), 0, stream>>>(Wqkv, Wout, Wff1, Wff2, Whead,
                                               pQkv, pOut, pFF1, pFF2, pHead);
  nca_k1<<<dim3(864), dim3(256), 0, stream>>>(x0, ln1s, ln1b, pQkv, qkvA, steps, 0);
  // s=0: read qkvA, write next-step qkvB; s=1: read qkvB (tail skipped)
  nca_kA<<<dim3(864), dim3(512), 0, stream>>>(qkvA, qkvB, pQkv, pOut, bout,
                                              ln1s, ln1b, ln2s, ln2b, pFF1, bff1,
                                              pFF2, bff2, ln3s, ln3b, pHead, bhead,
                                              x0, out, steps, 0);
  nca_kA<<<dim3(864), dim3(512), 0, stream>>>(qkvB, qkvA, pQkv, pOut, bout,
                                              ln1s, ln1b, ln2s, ln2b, pFF1, bff1,
                                              pFF2, bff2, ln3s, ln3b, pHead, bhead,
                                              out, out, steps, 1);
}